// Round 4
// baseline (1439.036 us; speedup 1.0000x reference)
//
#include <hip/hip_runtime.h>
#include <hip/hip_bf16.h>

typedef __hip_bfloat16 bf16;

#define NPTS  32768
#define NPB   4096
#define NPAIR (NPTS*16)
#define IMASK 32767
#define EPSB  1e-5f

// packed fp32 param-block offsets (floats)
#define O_WQ  0
#define O_BQ  4096
#define O_WK  4160
#define O_BK  8256
#define O_WV  8320
#define O_BV  12416
#define O_WP1 12480
#define O_BP1 12489
#define O_GP  12492
#define O_BTP 12495
#define O_WP2 12498
#define O_BP2 12690
#define O_G1  12754
#define O_BT1 12818
#define O_WW1 12882
#define O_BW1 13394
#define O_G2  13402
#define O_BT2 13410
#define O_WW2 13418
#define O_BW2 13482
#define NPRM  13490

__device__ __forceinline__ float b2f(bf16 v){ return __bfloat162float(v); }
__device__ __forceinline__ float u16f(unsigned short u){ return __uint_as_float(((unsigned)u)<<16); }
__device__ __forceinline__ float ldany(const void* p, long long i, int f32){
    return f32 ? ((const float*)p)[i] : b2f(((const bf16*)p)[i]);
}

// 2-way bf16 split: x ~= h + m (residual ~2^-17 |x|)
__device__ __forceinline__ void split2(float x, unsigned &h, unsigned &m){
    unsigned u  = __float_as_uint(x);
    unsigned hr = (u + 0x7FFFu + ((u>>16)&1u)) & 0xFFFF0000u;  // RTN-even bf16 (as fp32 bits)
    float xm = x - __uint_as_float(hr);                        // exact (Sterbenz)
    h = hr >> 16;
    m = __float_as_uint(xm) >> 16;                             // truncate
}

// ---------------------------------------------------------------- dtype sniff
__global__ __launch_bounds__(256) void k_sniff(const void* x, const void* wq, int* flags)
{
    __shared__ float red[2][4];
    const unsigned short* xu = (const unsigned short*)x;
    const unsigned short* wu = (const unsigned short*)wq;
    const int tid = threadIdx.x, lane = tid & 63, wvi = tid >> 6;
    float mx = fabsf(u16f(xu[tid]));
    float mw = fabsf(u16f(wu[tid]));
    for (int off = 32; off; off >>= 1){
        mx = fmaxf(mx, __shfl_down(mx, off));
        mw = fmaxf(mw, __shfl_down(mw, off));
    }
    if (lane == 0){ red[0][wvi] = mx; red[1][wvi] = mw; }
    __syncthreads();
    if (tid == 0){
        float ax = fmaxf(fmaxf(red[0][0], red[0][1]), fmaxf(red[0][2], red[0][3]));
        float aw = fmaxf(fmaxf(red[1][0], red[1][1]), fmaxf(red[1][2], red[1][3]));
        flags[0] = (ax > 1e6f) ? 1 : 0;
        flags[1] = (aw > 1e6f) ? 1 : 0;
    }
}

// ---------------------------------------------------------------- param canonicalization -> fp32 block
struct P20 { const void* p[20]; };

__global__ __launch_bounds__(256) void k_conv_prm(P20 t, const int* __restrict__ flags,
                                                  float* __restrict__ prm)
{
    const int i = blockIdx.x*256 + threadIdx.x;
    if (i >= NPRM) return;
    const int f = flags[1];
    const int sz[20] = {4096,64,4096,64,4096,64,9,3,3,3,192,64,64,64,512,8,8,8,64,8};
    int seg = 0, rem = i;
    while (rem >= sz[seg]){ rem -= sz[seg]; ++seg; }
    prm[i] = ldany(t.p[seg], rem, f);
}

__global__ __launch_bounds__(256) void k_conv_p(const void* __restrict__ p,
                                                const int* __restrict__ flags,
                                                float* __restrict__ p32)
{
    const int i = blockIdx.x*256 + threadIdx.x;
    if (i < NPTS*3) p32[i] = ldany(p, i, flags[0]);
}

// ---------------------------------------------------------------- projections (16 pts/block)
// Also emits pre-swizzled packed bf16 h/m planes of xk and xv for the KNN MFMA prune.
// Plane layout: row r (32 u32): 16B-slot pos holds unit u = pos ^ (r&7), i.e. elems [u*8,u*8+8)
// packed as 4 u32 (2 bf16 each). A linear tile copy then lands in swizzled LDS layout.
__global__ __launch_bounds__(256) void k_proj(
    const void* __restrict__ x, const int* __restrict__ flags,
    const float* __restrict__ prm,
    float* __restrict__ xq, float* __restrict__ xk, float* __restrict__ xv,
    float* __restrict__ sqk, float* __restrict__ sqv,
    unsigned* __restrict__ hkp, unsigned* __restrict__ mkp,
    unsigned* __restrict__ hvp, unsigned* __restrict__ mvp)
{
    __shared__ float WQ[4096], WK[4096], WV[4096], BQ[64], BK[64], BV[64];
    const int tid = threadIdx.x;
    for (int i = tid; i < 4096; i += 256){
        WQ[i] = prm[O_WQ+i]; WK[i] = prm[O_WK+i]; WV[i] = prm[O_WV+i];
    }
    if (tid < 64){ BQ[tid]=prm[O_BQ+tid]; BK[tid]=prm[O_BK+tid]; BV[tid]=prm[O_BV+tid]; }
    const int f32 = flags[0];
    __syncthreads();
    const int lane = tid & 63, wvi = tid >> 6;
    const int ptbase = blockIdx.x*16 + wvi*4;
    for (int it = 0; it < 4; ++it){
        const int pt = ptbase + it;
        float xl = ldany(x, (long long)pt*64 + lane, f32);
        float aq = BQ[lane], ak = BK[lane], av = BV[lane];
        #pragma unroll
        for (int k = 0; k < 64; ++k){
            float xb = __shfl(xl, k);
            aq += xb*WQ[k*64+lane];
            ak += xb*WK[k*64+lane];
            av += xb*WV[k*64+lane];
        }
        xq[pt*64+lane]=aq; xk[pt*64+lane]=ak; xv[pt*64+lane]=av;
        // bf16 h/m planes (pre-swizzled, packed pairs)
        unsigned hk16, mk16, hv16, mv16;
        split2(ak, hk16, mk16); split2(av, hv16, mv16);
        unsigned hkn = __shfl_down(hk16,1), mkn = __shfl_down(mk16,1);
        unsigned hvn = __shfl_down(hv16,1), mvn = __shfl_down(mv16,1);
        if (!(lane & 1)){
            const int u = lane >> 3, pos = u ^ (pt & 7);
            const size_t gi = (size_t)pt*32 + pos*4 + ((lane & 7) >> 1);
            hkp[gi] = hk16 | (hkn<<16);  mkp[gi] = mk16 | (mkn<<16);
            hvp[gi] = hv16 | (hvn<<16);  mvp[gi] = mv16 | (mvn<<16);
        }
        float s1 = ak*ak, s2 = av*av;
        for (int off=32; off; off>>=1){ s1 += __shfl_down(s1,off); s2 += __shfl_down(s2,off); }
        if (lane==0){ sqk[pt]=s1; sqv[pt]=s2; }
    }
}

// ---------------------------------------------------------------- KNN (MFMA prune + exact re-rank)
// grid 1024 (XCD-swizzled): kid = swz>>9 (0: k, 1: v); b = (swz>>6)&7, qt = swz&63.
// Block: 64 queries vs ALL 4096 cands of the batch (64 chunks of 64).
// Prune: 8-term h/m bf16 MFMA distance (err ~1.5e-4). Each of the 4 sub-lanes per query
//   owns a disjoint 16-column subset and keeps its own top-20 (subset containment is EXACT:
//   any overall top-16 member is within its lane's subset top-16; depth 20 = margin 4 vs noise).
// Exact: each lane recomputes its 20 survivors with the proven round-3 fmac sequence,
//   sorts (d,idx) keys, 4-way sorted merge on sub==0 emits top-16. Output == exact KNN.

using bfrag  = __attribute__((ext_vector_type(8))) short;   // 8 x bf16 (4 VGPRs)
using f32x4v = __attribute__((ext_vector_type(4))) float;   // MFMA accumulator

// swizzled LDS address (in shorts): row stride 64 shorts (128B), 16B units XOR'd by row&7
__device__ __forceinline__ int lds_sw(int row, int unit){
    return (row<<6) + (((unit ^ row) & 7)<<3);
}

__global__ __launch_bounds__(256, 4) void k_knn_part(
    const float* __restrict__ featk, const float* __restrict__ featv,
    const unsigned* __restrict__ hkp, const unsigned* __restrict__ mkp,
    const unsigned* __restrict__ hvp, const unsigned* __restrict__ mvp,
    const float* __restrict__ sqk, const float* __restrict__ sqv,
    int* __restrict__ idx_k, int* __restrict__ idx_v)
{
    __shared__ __attribute__((aligned(16))) unsigned char smem[40960];
    unsigned short* Ch = (unsigned short*)smem;                 // 8KB h-plane tile (swizzled)
    unsigned short* Cm = (unsigned short*)(smem + 8192);        // 8KB m-plane tile
    float* Dt  = (float*)(smem + 16384);                        // 64x68 dist tile (17408B)
    float* sqC = (float*)(smem + 16384 + 17408);                // 256B
    unsigned long long* Lbuf = (unsigned long long*)smem;       // merge phase (40960B overlay)

    const int tid = threadIdx.x;
    // XCD-aware swizzle: 1024 blocks = 8 XCDs x 128 contiguous logicals
    const int swz = ((int)blockIdx.x & 7) * 128 + ((int)blockIdx.x >> 3);
    const int kid = swz >> 9;
    const int bid = swz & 511;
    const float*    feat = kid ? featv : featk;
    const float*    sq   = kid ? sqv  : sqk;
    const unsigned* hpl  = kid ? hvp : hkp;
    const unsigned* mpl  = kid ? mvp : mkp;
    const int b  = bid >> 6;
    const int qt = bid & 63;
    const int q0 = b*NPB + qt*64;
    const int cb = b*NPB;

    const int lane = tid & 63, wv = tid >> 6;
    const int lq = lane & 15, lg = lane >> 4;        // MFMA fragment lane coords
    const int selq = (wv << 4) + (lane >> 2);        // selection row (0..63)
    const int sub  = lane & 3;
    const int row1 = tid >> 3, pos1 = tid & 7;       // staging: 16B-unit (row 0..31)
    const int row2 = row1 + 32;

    // ---- Q fragments from planes (register-resident, 2 planes x 2 k-steps)
    bfrag qh[2], qm[2];
    {
        const int qr = q0 + (wv<<4) + lq;
        #pragma unroll
        for (int ks = 0; ks < 2; ++ks){
            const int u0 = ks*4 + lg;
            const int pos = u0 ^ (qr & 7);
            union { uint4 u; bfrag v; } ch, cm;
            ch.u = *(const uint4*)&hpl[(size_t)qr*32 + pos*4];
            cm.u = *(const uint4*)&mpl[(size_t)qr*32 + pos*4];
            qh[ks] = ch.v; qm[ks] = cm.v;
        }
    }

    float dl[20]; int il[20];
    #pragma unroll
    for (int i=0;i<20;++i){ dl[i] = 3.4e38f; il[i] = 0; }

    const unsigned* hrow1 = hpl + (size_t)cb*32 + (size_t)row1*32 + pos1*4;
    const unsigned* hrow2 = hpl + (size_t)cb*32 + (size_t)row2*32 + pos1*4;
    const unsigned* mrow1 = mpl + (size_t)cb*32 + (size_t)row1*32 + pos1*4;
    const unsigned* mrow2 = mpl + (size_t)cb*32 + (size_t)row2*32 + pos1*4;
    const int ldsoff1 = row1*64 + pos1*8, ldsoff2 = row2*64 + pos1*8;

    // prologue: stage chunk 0
    {
        uint4 a1 = *(const uint4*)hrow1; uint4 a2 = *(const uint4*)hrow2;
        uint4 b1 = *(const uint4*)mrow1; uint4 b2 = *(const uint4*)mrow2;
        *(uint4*)&Ch[ldsoff1] = a1; *(uint4*)&Ch[ldsoff2] = a2;
        *(uint4*)&Cm[ldsoff1] = b1; *(uint4*)&Cm[ldsoff2] = b2;
        if (tid < 64) sqC[tid] = sq[cb + tid];
    }
    __syncthreads();

    #define MFMA_PHASE(CHN) { \
        const int coff = (CHN)*64; \
        _Pragma("unroll") \
        for (int ct = 0; ct < 4; ++ct){ \
            const int cd = ct*16 + lq; \
            union { uint4 u; bfrag v; } bh0u, bh1u, bm0u, bm1u; \
            bh0u.u = *(const uint4*)&Ch[lds_sw(cd, lg)]; \
            bh1u.u = *(const uint4*)&Ch[lds_sw(cd, 4+lg)]; \
            bm0u.u = *(const uint4*)&Cm[lds_sw(cd, lg)]; \
            bm1u.u = *(const uint4*)&Cm[lds_sw(cd, 4+lg)]; \
            f32x4v a = {0.f, 0.f, 0.f, 0.f}; \
            a = __builtin_amdgcn_mfma_f32_16x16x32_bf16(qm[0], bm0u.v, a, 0, 0, 0); \
            a = __builtin_amdgcn_mfma_f32_16x16x32_bf16(qm[1], bm1u.v, a, 0, 0, 0); \
            a = __builtin_amdgcn_mfma_f32_16x16x32_bf16(qh[0], bm0u.v, a, 0, 0, 0); \
            a = __builtin_amdgcn_mfma_f32_16x16x32_bf16(qm[0], bh0u.v, a, 0, 0, 0); \
            a = __builtin_amdgcn_mfma_f32_16x16x32_bf16(qh[1], bm1u.v, a, 0, 0, 0); \
            a = __builtin_amdgcn_mfma_f32_16x16x32_bf16(qm[1], bh1u.v, a, 0, 0, 0); \
            a = __builtin_amdgcn_mfma_f32_16x16x32_bf16(qh[0], bh0u.v, a, 0, 0, 0); \
            a = __builtin_amdgcn_mfma_f32_16x16x32_bf16(qh[1], bh1u.v, a, 0, 0, 0); \
            const float sc = sqC[ct*16 + lq]; \
            _Pragma("unroll") \
            for (int r = 0; r < 4; ++r) \
                Dt[((wv<<4) + (lg<<2) + r)*68 + ct*16 + lq] = sc - 2.f*a[r]; \
        } \
        (void)coff; }

    MFMA_PHASE(0)

    for (int chn = 0; chn < 64; ++chn){
        __syncthreads();   // Dt(chn) ready; planes consumed
        uint4 a1, a2, b1, b2; float sqr = 0.f;
        const bool more = (chn+1 < 64);
        if (more){
            const size_t co = (size_t)(chn+1)*2048;   // 64 rows * 32 u32
            a1 = *(const uint4*)(hrow1 + co); a2 = *(const uint4*)(hrow2 + co);
            b1 = *(const uint4*)(mrow1 + co); b2 = *(const uint4*)(mrow2 + co);
            if (tid < 64) sqr = sq[cb + (chn+1)*64 + tid];
        }
        // ---- per-sub-lane selection on Dt(chn): lane owns cols [sub*16, sub*16+16)
        {
            const int rowoff = selq*68 + sub*16;
            const int cbase  = cb + chn*64 + sub*16;
            #pragma unroll
            for (int r = 0; r < 4; ++r){
                float4 v = *(const float4*)&Dt[rowoff + 4*r];
                float vv[4] = {v.x, v.y, v.z, v.w};
                #pragma unroll
                for (int e = 0; e < 4; ++e){
                    float d = vv[e];
                    if (d < dl[19]){
                        int gi = cbase + 4*r + e;
                        #pragma unroll
                        for (int i = 19; i >= 1; --i){
                            bool sh   = dl[i-1] > d;
                            bool here = !sh && (dl[i] > d);
                            dl[i] = sh ? dl[i-1] : (here ? d  : dl[i]);
                            il[i] = sh ? il[i-1] : (here ? gi : il[i]);
                        }
                        bool h0 = dl[0] > d;
                        dl[0] = h0 ? d  : dl[0];
                        il[0] = h0 ? gi : il[0];
                    }
                }
            }
        }
        if (more){
            *(uint4*)&Ch[ldsoff1] = a1; *(uint4*)&Ch[ldsoff2] = a2;
            *(uint4*)&Cm[ldsoff1] = b1; *(uint4*)&Cm[ldsoff2] = b2;
            if (tid < 64) sqC[tid] = sqr;
        }
        __syncthreads();   // planes(chn+1) ready; Dt free
        if (more) MFMA_PHASE(chn+1)
    }

    // ---- exact re-rank (per lane, own 20 survivors): IDENTICAL arithmetic to round-3 proven code
    unsigned long long k64[20];
    {
        const float* qrow = feat + (size_t)(q0 + selq)*64;
        #pragma unroll
        for (int j = 0; j < 20; ++j){
            const int gi = il[j];
            const float* crow = feat + (size_t)gi*64;
            float acc = 0.f;
            #pragma unroll
            for (int k4 = 0; k4 < 16; ++k4){
                float4 qv = *(const float4*)&qrow[4*k4];
                float4 cv = *(const float4*)&crow[4*k4];
                acc += qv.x*cv.x; acc += qv.y*cv.y; acc += qv.z*cv.z; acc += qv.w*cv.w;
            }
            float d = sq[gi] - 2.f*acc;
            unsigned ud = __float_as_uint(d);
            ud ^= (ud & 0x80000000u) ? 0xFFFFFFFFu : 0x80000000u;   // order-preserving map
            k64[j] = ((unsigned long long)ud << 32) | (unsigned)gi; // (d, idx) lexicographic
        }
    }
    // odd-even sort of 20 keys (static indices)
    #pragma unroll
    for (int pass = 0; pass < 20; ++pass){
        #pragma unroll
        for (int i = (pass & 1); i + 1 < 20; i += 2){
            unsigned long long a = k64[i], bb = k64[i+1];
            bool sw = a > bb;
            k64[i]   = sw ? bb : a;
            k64[i+1] = sw ? a : bb;
        }
    }
    __syncthreads();   // smem reuse: planes/Dt dead
    #pragma unroll
    for (int j = 0; j < 20; ++j) Lbuf[(size_t)tid*20 + j] = k64[j];
    __syncthreads();
    if (sub == 0){
        const unsigned long long* L = &Lbuf[(size_t)tid*20];
        int p0 = 0, p1 = 20, p2 = 40, p3 = 60;
        int fi[16];
        #pragma unroll
        for (int o = 0; o < 16; ++o){
            unsigned long long b0 = L[p0], b1v = L[p1], b2v = L[p2], b3v = L[p3];
            unsigned long long m01 = (b0  < b1v) ? b0  : b1v;  int s01 = (b0  < b1v) ? 0 : 1;
            unsigned long long m23 = (b2v < b3v) ? b2v : b3v;  int s23 = (b2v < b3v) ? 2 : 3;
            unsigned long long mm  = (m01 < m23) ? m01 : m23;  int ss  = (m01 < m23) ? s01 : s23;
            fi[o] = (int)(unsigned)(mm & 0xFFFFFFFFull);
            if      (ss == 0) ++p0;
            else if (ss == 1) ++p1;
            else if (ss == 2) ++p2;
            else              ++p3;
        }
        int* idx_out = kid ? idx_v : idx_k;
        #pragma unroll
        for (int i4 = 0; i4 < 4; ++i4)
            *(int4*)&idx_out[(size_t)(q0+selq)*16 + 4*i4] =
                make_int4(fi[4*i4], fi[4*i4+1], fi[4*i4+2], fi[4*i4+3]);
    }
    #undef MFMA_PHASE
}

// ---------------------------------------------------------------- BN1 stats (reads idx_k)
__global__ __launch_bounds__(64) void k_bn1(
    const int* __restrict__ idx_k,
    const float* __restrict__ p32, const float* __restrict__ prm,
    float* __restrict__ part1)
{
    const int tid = threadIdx.x;
    const int blk = blockIdx.x;
    const size_t gq = (size_t)blk*64 + tid;
    int mi[16];
    #pragma unroll
    for (int o4 = 0; o4 < 4; ++o4){
        int4 v = *(const int4*)&idx_k[gq*16 + 4*o4];
        mi[4*o4]=v.x; mi[4*o4+1]=v.y; mi[4*o4+2]=v.z; mi[4*o4+3]=v.w;
    }
    const float w00=prm[O_WP1+0], w01=prm[O_WP1+1], w02=prm[O_WP1+2];
    const float w10=prm[O_WP1+3], w11=prm[O_WP1+4], w12=prm[O_WP1+5];
    const float w20=prm[O_WP1+6], w21=prm[O_WP1+7], w22=prm[O_WP1+8];
    const float bb0=prm[O_BP1+0], bb1=prm[O_BP1+1], bb2=prm[O_BP1+2];
    const float px=p32[gq*3+0], py=p32[gq*3+1], pz=p32[gq*3+2];
    float s0=0.f,s1=0.f,s2=0.f,t0=0.f,t1=0.f,t2=0.f;
    #pragma unroll
    for (int o = 0; o < 16; ++o){
        const int j = mi[o] & IMASK;
        float rx = p32[j*3+0]-px, ry = p32[j*3+1]-py, rz = p32[j*3+2]-pz;
        float h0 = bb0 + rx*w00 + ry*w10 + rz*w20;
        float h1 = bb1 + rx*w01 + ry*w11 + rz*w21;
        float h2 = bb2 + rx*w02 + ry*w12 + rz*w22;
        s0+=h0; s1+=h1; s2+=h2; t0+=h0*h0; t1+=h1*h1; t2+=h2*h2;
    }
    for (int off=32; off; off>>=1){
        s0+=__shfl_down(s0,off); s1+=__shfl_down(s1,off); s2+=__shfl_down(s2,off);
        t0+=__shfl_down(t0,off); t1+=__shfl_down(t1,off); t2+=__shfl_down(t2,off);
    }
    if (tid == 0){
        float* pp = part1 + blk*6;
        pp[0]=s0; pp[1]=s1; pp[2]=s2; pp[3]=t0; pp[4]=t1; pp[5]=t2;
    }
}

// ---------------------------------------------------------------- BN partial reduce -> affine
__global__ __launch_bounds__(256) void k_bnred(
    const float* __restrict__ part, int G, int C,
    const float* __restrict__ gamma, const float* __restrict__ beta,
    float* __restrict__ aff, float invCount)
{
    __shared__ float tot[128];
    const int tid = threadIdx.x, lane = tid & 63, wvi = tid >> 6;
    const int S = 2*C;
    for (int s = wvi; s < S; s += 4){
        float v = 0.f;
        for (int idx = lane; idx < G; idx += 64) v += part[(size_t)idx*S + s];
        for (int off=32; off; off>>=1) v += __shfl_down(v, off);
        if (lane == 0) tot[s] = v;
    }
    __syncthreads();
    if (tid < C){
        float mean = tot[tid]*invCount;
        float var  = fmaxf(tot[C+tid]*invCount - mean*mean, 0.f);
        float sc = gamma[tid] * rsqrtf(var + EPSB);
        aff[tid]   = sc;
        aff[C+tid] = beta[tid] - mean*sc;
    }
}

// ---------------------------------------------------------------- BN2 stats over r (unrolled x4)
__global__ __launch_bounds__(256) void k_rstats(
    const float* __restrict__ p32,
    const float* __restrict__ xq, const float* __restrict__ xk, const int* __restrict__ idx_k,
    const float* __restrict__ bn1aff, const float* __restrict__ prm,
    float* __restrict__ part2)
{
    const int tid = threadIdx.x, lane = tid & 63, wvi = tid >> 6;
    const float wa = prm[O_WP2+lane], wb = prm[O_WP2+64+lane], wc = prm[O_WP2+128+lane];
    const float bpc = prm[O_BP2+lane];
    const float w00=prm[O_WP1+0], w01=prm[O_WP1+1], w02=prm[O_WP1+2];
    const float w10=prm[O_WP1+3], w11=prm[O_WP1+4], w12=prm[O_WP1+5];
    const float w20=prm[O_WP1+6], w21=prm[O_WP1+7], w22=prm[O_WP1+8];
    const float bb0=prm[O_BP1+0], bb1=prm[O_BP1+1], bb2=prm[O_BP1+2];
    const float sc0=bn1aff[0], sc1=bn1aff[1], sc2=bn1aff[2];
    const float sh0=bn1aff[3], sh1=bn1aff[4], sh2=bn1aff[5];
    const int base = (blockIdx.x*4 + wvi) * 64;
    float asum=0.f, asq=0.f;
    float px=0.f, py=0.f, pz=0.f, xql=0.f;
    for (int e4 = 0; e4 < 16; ++e4){
        const int gb = base + e4*4;
        if ((gb & 15) == 0){
            const int n = gb >> 4;
            px=p32[n*3+0]; py=p32[n*3+1]; pz=p32[n*3+2];
            xql = xq[(size_t)n*64+lane];
        }
        int4 jj = *(const int4*)&idx_k[gb];
        int j[4] = { jj.x & IMASK, jj.y & IMASK, jj.z & IMASK, jj.w & IMASK };
        float kx[4], qx[4][3];
        #pragma unroll
        for (int u=0;u<4;++u){
            qx[u][0]=p32[j[u]*3+0]; qx[u][1]=p32[j[u]*3+1]; qx[u][2]=p32[j[u]*3+2];
            kx[u] = xk[(size_t)j[u]*64+lane];
        }
        #pragma unroll
        for (int u=0;u<4;++u){
            float rx = qx[u][0]-px, ry = qx[u][1]-py, rz = qx[u][2]-pz;
            float h0 = bb0 + rx*w00 + ry*w10 + rz*w20;
            float h1 = bb1 + rx*w01 + ry*w11 + rz*w21;
            float h2 = bb2 + rx*w02 + ry*w12 + rz*w22;
            float r0 = fmaxf(h0*sc0+sh0, 0.f), r1 = fmaxf(h1*sc1+sh1,0.f), r2 = fmaxf(h2*sc2+sh2,0.f);
            float pr = r0*wa + r1*wb + r2*wc + bpc;
            float rv = kx[u] - xql + pr;
            asum += rv; asq += rv*rv;
        }
    }
    __shared__ float red[4][128];
    red[wvi][lane] = asum; red[wvi][64+lane] = asq;
    __syncthreads();
    if (tid < 128) part2[(size_t)blockIdx.x*128 + tid] = red[0][tid]+red[1][tid]+red[2][tid]+red[3][tid];
}

// ---------------------------------------------------------------- BN3 stats over w (+ wbuf store)
__global__ __launch_bounds__(256) void k_wstats(
    const float* __restrict__ p32,
    const float* __restrict__ xq, const float* __restrict__ xk, const int* __restrict__ idx_k,
    const float* __restrict__ bn1aff, const float* __restrict__ prm,
    const float* __restrict__ bn2aff, float* __restrict__ wbuf, float* __restrict__ part3)
{
    __shared__ float4 PRW[64];
    __shared__ float2 SS2[64];
    __shared__ float4 W1A[64], W1B[64];
    const int tid = threadIdx.x;
    if (tid < 64){
        PRW[tid] = make_float4(prm[O_WP2+tid], prm[O_WP2+64+tid], prm[O_WP2+128+tid], prm[O_BP2+tid]);
        SS2[tid] = make_float2(bn2aff[tid], bn2aff[64+tid]);
        W1A[tid] = make_float4(prm[O_WW1+tid*8+0],prm[O_WW1+tid*8+1],prm[O_WW1+tid*8+2],prm[O_WW1+tid*8+3]);
        W1B[tid] = make_float4(prm[O_WW1+tid*8+4],prm[O_WW1+tid*8+5],prm[O_WW1+tid*8+6],prm[O_WW1+tid*8+7]);
    }
    __syncthreads();
    const int g = blockIdx.x*256 + tid;
    const int n = g >> 4;
    const int j = idx_k[g] & IMASK;
    const float w00=prm[O_WP1+0], w01=prm[O_WP1+1], w02=prm[O_WP1+2];
    const float w10=prm[O_WP1+3], w11=prm[O_WP1+4], w12=prm[O_WP1+5];
    const float w20=prm[O_WP1+6], w21=prm[O_WP1+7], w22=prm[O_WP1+8];
    const float bb0=prm[O_BP1+0], bb1=prm[O_BP1+1], bb2=prm[O_BP1+2];
    const float sc0=bn1aff[0], sc1=bn1aff[1], sc2=bn1aff[2];
    const float sh0=bn1aff[3], sh1=bn1aff[4], sh2=bn1aff[5];
    float rx = p32[j*3+0] - p32[n*3+0];
    float ry = p32[j*3+1] - p32[n*3+1];
    float rz = p32[j*3+2] - p32[n*3+2];
    float h0 = bb0 + rx*w00 + ry*w10 + rz*w20;
    float h1 = bb1 + rx*w01 + ry*w11 + rz*w21;
    float h2 = bb2 + rx*w02 + ry*w12 + rz*w22;
    float r0 = fmaxf(h0*sc0+sh0, 0.f), r1 = fmaxf(h1*sc1+sh1,0.f), r2 = fmaxf(h2*sc2+sh2,0.f);
    float wacc[8];
    #pragma unroll
    for (int i=0;i<8;++i) wacc[i] = prm[O_BW1+i];
    const float4* kr = (const float4*)(xk + (size_t)j*64);
    const float4* qr = (const float4*)(xq + (size_t)n*64);
    #pragma unroll
    for (int c4=0;c4<16;++c4){
        float4 kv = kr[c4], qv = qr[c4];
        float kvv[4] = {kv.x,kv.y,kv.z,kv.w};
        float qvv[4] = {qv.x,qv.y,qv.z,qv.w};
        #pragma unroll
        for (int d=0; d<4; ++d){
            int c = 4*c4 + d;
            float4 pw = PRW[c]; float2 ss = SS2[c];
            float pr = r0*pw.x + r1*pw.y + r2*pw.z + pw.w;
            float rr = kvv[d] - qvv[d] + pr;
            float y = fmaxf(rr*ss.x + ss.y, 0.f);
            float4 wA = W1A[c], wB = W1B[c];
            wacc[0]+=y*wA.x; wacc[1]+=y*wA.y; wacc[2]+=y*wA.z; wacc[3]+=y*wA.w;
            wacc[4]+=y*wB.x; wacc[5]+=y*wB.y; wacc[6]+=y*wB.z; wacc[7]+=y*wB.w;
        }
    }
    *(float4*)&wbuf[(size_t)g*8]   = make_float4(wacc[0],wacc[1],wacc[2],wacc[3]);
    *(float4*)&wbuf[(size_t)g*8+4] = make_float4(wacc[4],wacc[5],wacc[6],wacc[7]);
    float st[16];
    #pragma unroll
    for (int i=0;i<8;++i){ st[i]=wacc[i]; st[8+i]=wacc[i]*wacc[i]; }
    for (int off=32; off; off>>=1){
        #pragma unroll
        for (int k=0;k<16;++k) st[k] += __shfl_down(st[k], off);
    }
    __shared__ float red[4][16];
    const int lane = tid&63, wvi = tid>>6;
    if (lane==0){
        #pragma unroll
        for (int k=0;k<16;++k) red[wvi][k]=st[k];
    }
    __syncthreads();
    if (tid < 16) part3[(size_t)blockIdx.x*16 + tid] = red[0][tid]+red[1][tid]+red[2][tid]+red[3][tid];
}

// ---------------------------------------------------------------- final (reads wbuf; no shfl chain)
__global__ __launch_bounds__(256) void k_out(
    const float* __restrict__ p32, const float* __restrict__ xv,
    const int* __restrict__ idx_k, const int* __restrict__ idx_v,
    const float* __restrict__ bn1aff, const float* __restrict__ prm,
    const float* __restrict__ wbuf, const float* __restrict__ bn3aff,
    const int* __restrict__ flags, void* __restrict__ out)
{
    const int tid = threadIdx.x, lane = tid & 63, wvi = tid >> 6;
    const int n = blockIdx.x*4 + wvi;
    const int f32 = flags[0];
    const float w00=prm[O_WP1+0], w01=prm[O_WP1+1], w02=prm[O_WP1+2];
    const float w10=prm[O_WP1+3], w11=prm[O_WP1+4], w12=prm[O_WP1+5];
    const float w20=prm[O_WP1+6], w21=prm[O_WP1+7], w22=prm[O_WP1+8];
    const float bb0=prm[O_BP1+0], bb1=prm[O_BP1+1], bb2=prm[O_BP1+2];
    const float sc0=bn1aff[0], sc1=bn1aff[1], sc2=bn1aff[2];
    const float sh0=bn1aff[3], sh1=bn1aff[4], sh2=bn1aff[5];
    const float wa=prm[O_WP2+lane], wb=prm[O_WP2+64+lane], wc=prm[O_WP2+128+lane];
    const float bpc=prm[O_BP2+lane];
    const int i = lane & 7;
    float s3[8], t3[8], w2col[8];
    #pragma unroll
    for (int m=0;m<8;++m){
        s3[m]=bn3aff[m]; t3[m]=bn3aff[8+m];
        w2col[m]=prm[O_WW2+m*8+i];
    }
    const float bw2i = prm[O_BW2+i];
    const float px=p32[n*3+0], py=p32[n*3+1], pz=p32[n*3+2];
    float comb[16], wf[16];
    #pragma unroll
    for (int t=0;t<16;++t){
        const int g = n*16 + t;
        const int jk = idx_k[g] & IMASK;
        const int jv = idx_v[g] & IMASK;
        float rx=p32[jk*3+0]-px, ry=p32[jk*3+1]-py, rz=p32[jk*3+2]-pz;
        float h0=bb0+rx*w00+ry*w10+rz*w20;
        float h1=bb1+rx*w01+ry*w11+rz*w21;
        float h2=bb2+rx*w02+ry*w12+rz*w22;
        float r0=fmaxf(h0*sc0+sh0,0.f), r1=fmaxf(h1*sc1+sh1,0.f), r2=fmaxf(h2*sc2+sh2,0.f);
        float pr=r0*wa+r1*wb+r2*wc+bpc;
        float4 wA = *(const float4*)&wbuf[(size_t)g*8];
        float4 wB = *(const float4*)&wbuf[(size_t)g*8+4];
        float wm[8] = {wA.x,wA.y,wA.z,wA.w,wB.x,wB.y,wB.z,wB.w};
        float acc = bw2i;
        #pragma unroll
        for (int m=0;m<8;++m){
            float y3 = fmaxf(wm[m]*s3[m]+t3[m],0.f);
            acc += y3*w2col[m];
        }
        wf[t]=acc;
        comb[t]=xv[(size_t)jv*64+lane]+pr;
    }
    float mx = wf[0];
    #pragma unroll
    for (int t=1;t<16;++t) mx = fmaxf(mx, wf[t]);
    float ssum=0.f, osum=0.f;
    #pragma unroll
    for (int t=0;t<16;++t){ float e = __expf(wf[t]-mx); ssum += e; osum += e*comb[t]; }
    const float v = osum / ssum;
    if (f32) ((float*)out)[(size_t)n*64+lane] = v;
    else     ((bf16*)out)[(size_t)n*64+lane] = __float2bfloat16(v);
}

// ---------------------------------------------------------------- launcher
extern "C" void kernel_launch(void* const* d_in, const int* in_sizes, int n_in,
                              void* d_out, int out_size, void* d_ws, size_t ws_size,
                              hipStream_t stream)
{
    const void* p  = d_in[0];
    const void* x  = d_in[1];
    P20 prms;
    for (int i = 0; i < 20; ++i) prms.p[i] = d_in[3+i];

    // workspace layout (floats) — within the 48.08 MB proven footprint
    float* W = (float*)d_ws;
    float* xqf    = W + 0;
    float* xkf    = W + 2097152;
    float* xvf    = W + 4194304;
    float* sqk    = W + 6291456;
    float* sqv    = W + 6324224;
    int*   idx_k  = (int*)(W + 6356992);
    int*   idx_v  = (int*)(W + 6881280);
    float* p32    = W + 7405568;   // 98304
    float* prm    = W + 7503872;   // 13490 (+pad)
    float* part1  = W + 7517376;   // 512*6 (slack)
    float* part2  = W + 7529664;   // 2048*128
    float* part3  = W + 7791808;   // 2048*16
    float* bn1aff = W + 7824576;   // 16
    float* bn2aff = W + 7824592;   // 128
    float* bn3aff = W + 7824720;   // 16
    int*   flags  = (int*)(W + 7824736); // 2 (+pad to 16)
    // overlay region (4,194,304 floats): bf16 h/m planes (live: k_proj -> k_knn_part),
    // then wbuf (written k_wstats, read k_out) — disjoint lifetimes.
    unsigned* hkp = (unsigned*)(W + 7824752);             // 1,048,576 u32
    unsigned* mkp = (unsigned*)(W + 7824752 + 1048576);
    unsigned* hvp = (unsigned*)(W + 7824752 + 2097152);
    unsigned* mvp = (unsigned*)(W + 7824752 + 3145728);
    float* wbuf   = W + 7824752;   // 4,194,304

    const float invP = 1.f / (float)NPAIR;

    k_sniff<<<1,256,0,stream>>>(x, d_in[3], flags);
    k_conv_prm<<<(NPRM+255)/256,256,0,stream>>>(prms, flags, prm);
    k_conv_p<<<(NPTS*3+255)/256,256,0,stream>>>(p, flags, p32);
    k_proj<<<2048,256,0,stream>>>(x, flags, prm, xqf,xkf,xvf, sqk,sqv, hkp,mkp,hvp,mvp);
    k_knn_part<<<1024,256,0,stream>>>(xkf, xvf, hkp,mkp,hvp,mvp, sqk, sqv, idx_k, idx_v);
    k_bn1<<<512,64,0,stream>>>(idx_k, p32, prm, part1);
    k_bnred<<<1,256,0,stream>>>(part1, 512, 3, prm+O_GP, prm+O_BTP, bn1aff, invP);
    k_rstats<<<2048,256,0,stream>>>(p32, xqf, xkf, idx_k, bn1aff, prm, part2);
    k_bnred<<<1,256,0,stream>>>(part2, 2048, 64, prm+O_G1, prm+O_BT1, bn2aff, invP);
    k_wstats<<<2048,256,0,stream>>>(p32, xqf, xkf, idx_k, bn1aff, prm, bn2aff, wbuf, part3);
    k_bnred<<<1,256,0,stream>>>(part3, 2048, 8, prm+O_G2, prm+O_BT2, bn3aff, invP);
    k_out<<<8192,256,0,stream>>>(p32, xvf, idx_k, idx_v, bn1aff, prm,
                                 wbuf, bn3aff, flags, d_out);
}

// Round 5
// 957.945 us; speedup vs baseline: 1.5022x; 1.5022x over previous
//
#include <hip/hip_runtime.h>
#include <hip/hip_bf16.h>

typedef __hip_bfloat16 bf16;

#define NPTS  32768
#define NPB   4096
#define NPAIR (NPTS*16)
#define IMASK 32767
#define EPSB  1e-5f

// packed fp32 param-block offsets (floats)
#define O_WQ  0
#define O_BQ  4096
#define O_WK  4160
#define O_BK  8256
#define O_WV  8320
#define O_BV  12416
#define O_WP1 12480
#define O_BP1 12489
#define O_GP  12492
#define O_BTP 12495
#define O_WP2 12498
#define O_BP2 12690
#define O_G1  12754
#define O_BT1 12818
#define O_WW1 12882
#define O_BW1 13394
#define O_G2  13402
#define O_BT2 13410
#define O_WW2 13418
#define O_BW2 13482
#define NPRM  13490

__device__ __forceinline__ float b2f(bf16 v){ return __bfloat162float(v); }
__device__ __forceinline__ float u16f(unsigned short u){ return __uint_as_float(((unsigned)u)<<16); }
__device__ __forceinline__ float ldany(const void* p, long long i, int f32){
    return f32 ? ((const float*)p)[i] : b2f(((const bf16*)p)[i]);
}

// 2-way bf16 split: x ~= h + m (residual ~2^-17 |x|)
__device__ __forceinline__ void split2(float x, unsigned &h, unsigned &m){
    unsigned u  = __float_as_uint(x);
    unsigned hr = (u + 0x7FFFu + ((u>>16)&1u)) & 0xFFFF0000u;  // RTN-even bf16 (as fp32 bits)
    float xm = x - __uint_as_float(hr);                        // exact (Sterbenz)
    h = hr >> 16;
    m = __float_as_uint(xm) >> 16;                             // truncate
}

// ---------------------------------------------------------------- dtype sniff
__global__ __launch_bounds__(256) void k_sniff(const void* x, const void* wq, int* flags)
{
    __shared__ float red[2][4];
    const unsigned short* xu = (const unsigned short*)x;
    const unsigned short* wu = (const unsigned short*)wq;
    const int tid = threadIdx.x, lane = tid & 63, wvi = tid >> 6;
    float mx = fabsf(u16f(xu[tid]));
    float mw = fabsf(u16f(wu[tid]));
    for (int off = 32; off; off >>= 1){
        mx = fmaxf(mx, __shfl_down(mx, off));
        mw = fmaxf(mw, __shfl_down(mw, off));
    }
    if (lane == 0){ red[0][wvi] = mx; red[1][wvi] = mw; }
    __syncthreads();
    if (tid == 0){
        float ax = fmaxf(fmaxf(red[0][0], red[0][1]), fmaxf(red[0][2], red[0][3]));
        float aw = fmaxf(fmaxf(red[1][0], red[1][1]), fmaxf(red[1][2], red[1][3]));
        flags[0] = (ax > 1e6f) ? 1 : 0;
        flags[1] = (aw > 1e6f) ? 1 : 0;
    }
}

// ---------------------------------------------------------------- param canonicalization -> fp32 block
struct P20 { const void* p[20]; };

__global__ __launch_bounds__(256) void k_conv_prm(P20 t, const int* __restrict__ flags,
                                                  float* __restrict__ prm)
{
    const int i = blockIdx.x*256 + threadIdx.x;
    if (i >= NPRM) return;
    const int f = flags[1];
    const int sz[20] = {4096,64,4096,64,4096,64,9,3,3,3,192,64,64,64,512,8,8,8,64,8};
    int seg = 0, rem = i;
    while (rem >= sz[seg]){ rem -= sz[seg]; ++seg; }
    prm[i] = ldany(t.p[seg], rem, f);
}

__global__ __launch_bounds__(256) void k_conv_p(const void* __restrict__ p,
                                                const int* __restrict__ flags,
                                                float* __restrict__ p32)
{
    const int i = blockIdx.x*256 + threadIdx.x;
    if (i < NPTS*3) p32[i] = ldany(p, i, flags[0]);
}

// ---------------------------------------------------------------- projections (16 pts/block)
// Emits pre-swizzled packed bf16 h/m planes of xk and xv for the KNN MFMA prune.
__global__ __launch_bounds__(256) void k_proj(
    const void* __restrict__ x, const int* __restrict__ flags,
    const float* __restrict__ prm,
    float* __restrict__ xq, float* __restrict__ xk, float* __restrict__ xv,
    float* __restrict__ sqk, float* __restrict__ sqv,
    unsigned* __restrict__ hkp, unsigned* __restrict__ mkp,
    unsigned* __restrict__ hvp, unsigned* __restrict__ mvp)
{
    __shared__ float WQ[4096], WK[4096], WV[4096], BQ[64], BK[64], BV[64];
    const int tid = threadIdx.x;
    for (int i = tid; i < 4096; i += 256){
        WQ[i] = prm[O_WQ+i]; WK[i] = prm[O_WK+i]; WV[i] = prm[O_WV+i];
    }
    if (tid < 64){ BQ[tid]=prm[O_BQ+tid]; BK[tid]=prm[O_BK+tid]; BV[tid]=prm[O_BV+tid]; }
    const int f32 = flags[0];
    __syncthreads();
    const int lane = tid & 63, wvi = tid >> 6;
    const int ptbase = blockIdx.x*16 + wvi*4;
    for (int it = 0; it < 4; ++it){
        const int pt = ptbase + it;
        float xl = ldany(x, (long long)pt*64 + lane, f32);
        float aq = BQ[lane], ak = BK[lane], av = BV[lane];
        #pragma unroll
        for (int k = 0; k < 64; ++k){
            float xb = __shfl(xl, k);
            aq += xb*WQ[k*64+lane];
            ak += xb*WK[k*64+lane];
            av += xb*WV[k*64+lane];
        }
        xq[pt*64+lane]=aq; xk[pt*64+lane]=ak; xv[pt*64+lane]=av;
        unsigned hk16, mk16, hv16, mv16;
        split2(ak, hk16, mk16); split2(av, hv16, mv16);
        unsigned hkn = __shfl_down(hk16,1), mkn = __shfl_down(mk16,1);
        unsigned hvn = __shfl_down(hv16,1), mvn = __shfl_down(mv16,1);
        if (!(lane & 1)){
            const int u = lane >> 3, pos = u ^ (pt & 7);
            const size_t gi = (size_t)pt*32 + pos*4 + ((lane & 7) >> 1);
            hkp[gi] = hk16 | (hkn<<16);  mkp[gi] = mk16 | (mkn<<16);
            hvp[gi] = hv16 | (hvn<<16);  mvp[gi] = mv16 | (mvn<<16);
        }
        float s1 = ak*ak, s2 = av*av;
        for (int off=32; off; off>>=1){ s1 += __shfl_down(s1,off); s2 += __shfl_down(s2,off); }
        if (lane==0){ sqk[pt]=s1; sqv[pt]=s2; }
    }
}

// ---------------------------------------------------------------- KNN (MFMA prune + exact re-rank)
// grid 1024 (XCD-swizzled). Block: 64 queries vs ALL 4096 cands of the batch (64 chunks).
// Prune: 8-term h/m bf16 MFMA distance (round-4 proven); OWNER-LANE mask-filter + depth-20
//   insertion (round-3 proven perf structure — wave pays max over 16 owners, not lane union).
// Tail (spill-free): 20 survivors split 5/sub-lane; exact VALU recompute (bit-identical to
//   the proven round-3 fmac sequence); static sort-5; LDS 4-way sorted merge -> top-16.

using bfrag  = __attribute__((ext_vector_type(8))) short;   // 8 x bf16 (4 VGPRs)
using f32x4v = __attribute__((ext_vector_type(4))) float;   // MFMA accumulator

// swizzled LDS address (in shorts): row stride 64 shorts (128B), 16B units XOR'd by row&7
__device__ __forceinline__ int lds_sw(int row, int unit){
    return (row<<6) + (((unit ^ row) & 7)<<3);
}

__global__ __launch_bounds__(256, 4) void k_knn_part(
    const float* __restrict__ featk, const float* __restrict__ featv,
    const unsigned* __restrict__ hkp, const unsigned* __restrict__ mkp,
    const unsigned* __restrict__ hvp, const unsigned* __restrict__ mvp,
    const float* __restrict__ sqk, const float* __restrict__ sqv,
    int* __restrict__ idx_k, int* __restrict__ idx_v)
{
    __shared__ __attribute__((aligned(16))) unsigned char smem[34048];
    unsigned short* Ch = (unsigned short*)smem;                 // 8KB h-plane tile (swizzled)
    unsigned short* Cm = (unsigned short*)(smem + 8192);        // 8KB m-plane tile
    float* Dt  = (float*)(smem + 16384);                        // 64x68 dist tile (17408B)
    float* sqC = (float*)(smem + 16384 + 17408);                // 256B
    unsigned long long* Lbuf = (unsigned long long*)smem;       // tail overlay (256*6*8=12288B)

    const int tid = threadIdx.x;
    // XCD-aware swizzle: 1024 blocks = 8 XCDs x 128 contiguous logicals
    const int swz = ((int)blockIdx.x & 7) * 128 + ((int)blockIdx.x >> 3);
    const int kid = swz >> 9;
    const int bid = swz & 511;
    const float*    feat = kid ? featv : featk;
    const float*    sq   = kid ? sqv  : sqk;
    const unsigned* hpl  = kid ? hvp : hkp;
    const unsigned* mpl  = kid ? mvp : mkp;
    const int b  = bid >> 6;
    const int qt = bid & 63;
    const int q0 = b*NPB + qt*64;
    const int cb = b*NPB;

    const int lane = tid & 63, wv = tid >> 6;
    const int lq = lane & 15, lg = lane >> 4;        // MFMA fragment lane coords
    const int selq = (wv << 4) + (lane >> 2);        // selection row (0..63)
    const int sub  = lane & 3;
    const int owner = lane & ~3;
    const int row1 = tid >> 3, pos1 = tid & 7;       // staging: 16B-unit coords
    const int row2 = row1 + 32;

    // ---- Q fragments from planes (register-resident, 2 planes x 2 k-steps)
    bfrag qh[2], qm[2];
    {
        const int qr = q0 + (wv<<4) + lq;
        #pragma unroll
        for (int ks = 0; ks < 2; ++ks){
            const int u0 = ks*4 + lg;
            const int pos = u0 ^ (qr & 7);
            union { uint4 u; bfrag v; } ch, cm;
            ch.u = *(const uint4*)&hpl[(size_t)qr*32 + pos*4];
            cm.u = *(const uint4*)&mpl[(size_t)qr*32 + pos*4];
            qh[ks] = ch.v; qm[ks] = cm.v;
        }
    }

    float dl[20]; int il[20];
    #pragma unroll
    for (int i=0;i<20;++i){ dl[i] = 3.4e38f; il[i] = 0; }

    const unsigned* hrow1 = hpl + (size_t)cb*32 + (size_t)row1*32 + pos1*4;
    const unsigned* hrow2 = hpl + (size_t)cb*32 + (size_t)row2*32 + pos1*4;
    const unsigned* mrow1 = mpl + (size_t)cb*32 + (size_t)row1*32 + pos1*4;
    const unsigned* mrow2 = mpl + (size_t)cb*32 + (size_t)row2*32 + pos1*4;
    const int ldsoff1 = row1*64 + pos1*8, ldsoff2 = row2*64 + pos1*8;

    // prologue: stage chunk 0
    {
        uint4 a1 = *(const uint4*)hrow1; uint4 a2 = *(const uint4*)hrow2;
        uint4 b1 = *(const uint4*)mrow1; uint4 b2 = *(const uint4*)mrow2;
        *(uint4*)&Ch[ldsoff1] = a1; *(uint4*)&Ch[ldsoff2] = a2;
        *(uint4*)&Cm[ldsoff1] = b1; *(uint4*)&Cm[ldsoff2] = b2;
        if (tid < 64) sqC[tid] = sq[cb + tid];
    }
    __syncthreads();

    #define MFMA_PHASE() { \
        _Pragma("unroll") \
        for (int ct = 0; ct < 4; ++ct){ \
            const int cd = ct*16 + lq; \
            union { uint4 u; bfrag v; } bh0u, bh1u, bm0u, bm1u; \
            bh0u.u = *(const uint4*)&Ch[lds_sw(cd, lg)]; \
            bh1u.u = *(const uint4*)&Ch[lds_sw(cd, 4+lg)]; \
            bm0u.u = *(const uint4*)&Cm[lds_sw(cd, lg)]; \
            bm1u.u = *(const uint4*)&Cm[lds_sw(cd, 4+lg)]; \
            f32x4v a = {0.f, 0.f, 0.f, 0.f}; \
            a = __builtin_amdgcn_mfma_f32_16x16x32_bf16(qm[0], bm0u.v, a, 0, 0, 0); \
            a = __builtin_amdgcn_mfma_f32_16x16x32_bf16(qm[1], bm1u.v, a, 0, 0, 0); \
            a = __builtin_amdgcn_mfma_f32_16x16x32_bf16(qh[0], bm0u.v, a, 0, 0, 0); \
            a = __builtin_amdgcn_mfma_f32_16x16x32_bf16(qm[0], bh0u.v, a, 0, 0, 0); \
            a = __builtin_amdgcn_mfma_f32_16x16x32_bf16(qh[1], bm1u.v, a, 0, 0, 0); \
            a = __builtin_amdgcn_mfma_f32_16x16x32_bf16(qm[1], bh1u.v, a, 0, 0, 0); \
            a = __builtin_amdgcn_mfma_f32_16x16x32_bf16(qh[0], bh0u.v, a, 0, 0, 0); \
            a = __builtin_amdgcn_mfma_f32_16x16x32_bf16(qh[1], bh1u.v, a, 0, 0, 0); \
            const float sc = sqC[ct*16 + lq]; \
            _Pragma("unroll") \
            for (int r = 0; r < 4; ++r) \
                Dt[((wv<<4) + (lg<<2) + r)*68 + ct*16 + lq] = sc - 2.f*a[r]; \
        } }

    MFMA_PHASE()

    for (int chn = 0; chn < 64; ++chn){
        __syncthreads();   // Dt(chn) ready; Ch/Cm consumed by MFMA(chn)
        const bool more = (chn+1 < 64);
        uint4 a1, a2, b1, b2; float sqr = 0.f;
        if (more){
            const size_t co = (size_t)(chn+1)*2048;   // 64 rows * 32 u32
            a1 = *(const uint4*)(hrow1 + co); a2 = *(const uint4*)(hrow2 + co);
            b1 = *(const uint4*)(mrow1 + co); b2 = *(const uint4*)(mrow2 + co);
            if (tid < 64) sqr = sq[cb + (chn+1)*64 + tid];
        }
        // ---- owner-lane selection on Dt(chn): mask filter + depth-20 insertion (round-3 core)
        {
            float worst = __shfl(dl[19], owner);
            unsigned m16 = 0;
            const int rowoff = selq*68 + sub*16;
            #pragma unroll
            for (int r = 0; r < 4; ++r){
                float4 v = *(const float4*)&Dt[rowoff + 4*r];
                m16 |= (v.x < worst ? 1u : 0u) << (4*r+0);
                m16 |= (v.y < worst ? 1u : 0u) << (4*r+1);
                m16 |= (v.z < worst ? 1u : 0u) << (4*r+2);
                m16 |= (v.w < worst ? 1u : 0u) << (4*r+3);
            }
            unsigned ma = __shfl(m16, owner+0), mb = __shfl(m16, owner+1);
            unsigned mc = __shfl(m16, owner+2), md = __shfl(m16, owner+3);
            if (sub == 0){
                unsigned long long m = (unsigned long long)ma
                                     | ((unsigned long long)mb << 16)
                                     | ((unsigned long long)mc << 32)
                                     | ((unsigned long long)md << 48);
                const int qrow = selq*68;
                const int c0 = cb + chn*64;
                while (m){
                    int c = (int)__builtin_ctzll(m); m &= m - 1;
                    float d = Dt[qrow + c];
                    if (d < dl[19]){
                        int gi = c0 + c;
                        #pragma unroll
                        for (int i = 19; i >= 1; --i){
                            bool sh   = dl[i-1] > d;
                            bool here = !sh && (dl[i] > d);
                            dl[i] = sh ? dl[i-1] : (here ? d  : dl[i]);
                            il[i] = sh ? il[i-1] : (here ? gi : il[i]);
                        }
                        bool h0 = dl[0] > d;
                        dl[0] = h0 ? d  : dl[0];
                        il[0] = h0 ? gi : il[0];
                    }
                }
            }
        }
        if (more){
            *(uint4*)&Ch[ldsoff1] = a1; *(uint4*)&Ch[ldsoff2] = a2;
            *(uint4*)&Cm[ldsoff1] = b1; *(uint4*)&Cm[ldsoff2] = b2;
            if (tid < 64) sqC[tid] = sqr;
        }
        __syncthreads();   // planes(chn+1) staged; Dt free
        if (more) MFMA_PHASE()
    }
    #undef MFMA_PHASE

    // ---- tail: distribute 20 survivors, 5 per sub-lane
    int cidx[5];
    #pragma unroll
    for (int j = 0; j < 20; ++j){
        int gi = __shfl(il[j], owner);
        if ((j & 3) == sub) cidx[j >> 2] = gi;
    }
    // exact VALU distance — IDENTICAL arithmetic to the proven round-3 code
    unsigned long long k5[5];
    {
        const float* qrow = feat + (size_t)(q0 + selq)*64;
        #pragma unroll
        for (int s = 0; s < 5; ++s){
            const int gi = cidx[s];
            const float* crow = feat + (size_t)gi*64;
            float acc = 0.f;
            #pragma unroll
            for (int k4 = 0; k4 < 16; ++k4){
                float4 qv = *(const float4*)&qrow[4*k4];
                float4 cv = *(const float4*)&crow[4*k4];
                acc += qv.x*cv.x; acc += qv.y*cv.y; acc += qv.z*cv.z; acc += qv.w*cv.w;
            }
            float d = sq[gi] - 2.f*acc;
            unsigned ud = __float_as_uint(d);
            ud ^= (ud & 0x80000000u) ? 0xFFFFFFFFu : 0x80000000u;   // order-preserving map
            k5[s] = ((unsigned long long)ud << 32) | (unsigned)gi;  // (d, idx) lexicographic
        }
    }
    // static odd-even sort of 5 keys
    #pragma unroll
    for (int pass = 0; pass < 5; ++pass){
        #pragma unroll
        for (int i = (pass & 1); i + 1 < 5; i += 2){
            unsigned long long a = k5[i], bb = k5[i+1];
            bool sw = a > bb;
            k5[i]   = sw ? bb : a;
            k5[i+1] = sw ? a : bb;
        }
    }
    __syncthreads();   // smem reuse: planes/Dt dead
    #pragma unroll
    for (int j = 0; j < 5; ++j) Lbuf[(size_t)tid*6 + j] = k5[j];
    Lbuf[(size_t)tid*6 + 5] = ~0ull;   // sentinel
    __syncthreads();
    if (sub == 0){
        const unsigned long long* L0 = &Lbuf[(size_t)(tid+0)*6];
        const unsigned long long* L1 = &Lbuf[(size_t)(tid+1)*6];
        const unsigned long long* L2 = &Lbuf[(size_t)(tid+2)*6];
        const unsigned long long* L3 = &Lbuf[(size_t)(tid+3)*6];
        int p0 = 0, p1 = 0, p2 = 0, p3 = 0;
        int fi[16];
        #pragma unroll
        for (int o = 0; o < 16; ++o){
            unsigned long long b0 = L0[p0], b1v = L1[p1], b2v = L2[p2], b3v = L3[p3];
            unsigned long long m01 = (b0  < b1v) ? b0  : b1v;  int s01 = (b0  < b1v) ? 0 : 1;
            unsigned long long m23 = (b2v < b3v) ? b2v : b3v;  int s23 = (b2v < b3v) ? 2 : 3;
            unsigned long long mm  = (m01 < m23) ? m01 : m23;  int ss  = (m01 < m23) ? s01 : s23;
            fi[o] = (int)(unsigned)(mm & 0xFFFFFFFFull);
            if      (ss == 0) ++p0;
            else if (ss == 1) ++p1;
            else if (ss == 2) ++p2;
            else              ++p3;
        }
        int* idx_out = kid ? idx_v : idx_k;
        #pragma unroll
        for (int i4 = 0; i4 < 4; ++i4)
            *(int4*)&idx_out[(size_t)(q0+selq)*16 + 4*i4] =
                make_int4(fi[4*i4], fi[4*i4+1], fi[4*i4+2], fi[4*i4+3]);
    }
}

// ---------------------------------------------------------------- BN1 stats (reads idx_k)
__global__ __launch_bounds__(64) void k_bn1(
    const int* __restrict__ idx_k,
    const float* __restrict__ p32, const float* __restrict__ prm,
    float* __restrict__ part1)
{
    const int tid = threadIdx.x;
    const int blk = blockIdx.x;
    const size_t gq = (size_t)blk*64 + tid;
    int mi[16];
    #pragma unroll
    for (int o4 = 0; o4 < 4; ++o4){
        int4 v = *(const int4*)&idx_k[gq*16 + 4*o4];
        mi[4*o4]=v.x; mi[4*o4+1]=v.y; mi[4*o4+2]=v.z; mi[4*o4+3]=v.w;
    }
    const float w00=prm[O_WP1+0], w01=prm[O_WP1+1], w02=prm[O_WP1+2];
    const float w10=prm[O_WP1+3], w11=prm[O_WP1+4], w12=prm[O_WP1+5];
    const float w20=prm[O_WP1+6], w21=prm[O_WP1+7], w22=prm[O_WP1+8];
    const float bb0=prm[O_BP1+0], bb1=prm[O_BP1+1], bb2=prm[O_BP1+2];
    const float px=p32[gq*3+0], py=p32[gq*3+1], pz=p32[gq*3+2];
    float s0=0.f,s1=0.f,s2=0.f,t0=0.f,t1=0.f,t2=0.f;
    #pragma unroll
    for (int o = 0; o < 16; ++o){
        const int j = mi[o] & IMASK;
        float rx = p32[j*3+0]-px, ry = p32[j*3+1]-py, rz = p32[j*3+2]-pz;
        float h0 = bb0 + rx*w00 + ry*w10 + rz*w20;
        float h1 = bb1 + rx*w01 + ry*w11 + rz*w21;
        float h2 = bb2 + rx*w02 + ry*w12 + rz*w22;
        s0+=h0; s1+=h1; s2+=h2; t0+=h0*h0; t1+=h1*h1; t2+=h2*h2;
    }
    for (int off=32; off; off>>=1){
        s0+=__shfl_down(s0,off); s1+=__shfl_down(s1,off); s2+=__shfl_down(s2,off);
        t0+=__shfl_down(t0,off); t1+=__shfl_down(t1,off); t2+=__shfl_down(t2,off);
    }
    if (tid == 0){
        float* pp = part1 + blk*6;
        pp[0]=s0; pp[1]=s1; pp[2]=s2; pp[3]=t0; pp[4]=t1; pp[5]=t2;
    }
}

// ---------------------------------------------------------------- BN partial reduce -> affine
__global__ __launch_bounds__(256) void k_bnred(
    const float* __restrict__ part, int G, int C,
    const float* __restrict__ gamma, const float* __restrict__ beta,
    float* __restrict__ aff, float invCount)
{
    __shared__ float tot[128];
    const int tid = threadIdx.x, lane = tid & 63, wvi = tid >> 6;
    const int S = 2*C;
    for (int s = wvi; s < S; s += 4){
        float v = 0.f;
        for (int idx = lane; idx < G; idx += 64) v += part[(size_t)idx*S + s];
        for (int off=32; off; off>>=1) v += __shfl_down(v, off);
        if (lane == 0) tot[s] = v;
    }
    __syncthreads();
    if (tid < C){
        float mean = tot[tid]*invCount;
        float var  = fmaxf(tot[C+tid]*invCount - mean*mean, 0.f);
        float sc = gamma[tid] * rsqrtf(var + EPSB);
        aff[tid]   = sc;
        aff[C+tid] = beta[tid] - mean*sc;
    }
}

// ---------------------------------------------------------------- BN2 stats over r (unrolled x4)
__global__ __launch_bounds__(256) void k_rstats(
    const float* __restrict__ p32,
    const float* __restrict__ xq, const float* __restrict__ xk, const int* __restrict__ idx_k,
    const float* __restrict__ bn1aff, const float* __restrict__ prm,
    float* __restrict__ part2)
{
    const int tid = threadIdx.x, lane = tid & 63, wvi = tid >> 6;
    const float wa = prm[O_WP2+lane], wb = prm[O_WP2+64+lane], wc = prm[O_WP2+128+lane];
    const float bpc = prm[O_BP2+lane];
    const float w00=prm[O_WP1+0], w01=prm[O_WP1+1], w02=prm[O_WP1+2];
    const float w10=prm[O_WP1+3], w11=prm[O_WP1+4], w12=prm[O_WP1+5];
    const float w20=prm[O_WP1+6], w21=prm[O_WP1+7], w22=prm[O_WP1+8];
    const float bb0=prm[O_BP1+0], bb1=prm[O_BP1+1], bb2=prm[O_BP1+2];
    const float sc0=bn1aff[0], sc1=bn1aff[1], sc2=bn1aff[2];
    const float sh0=bn1aff[3], sh1=bn1aff[4], sh2=bn1aff[5];
    const int base = (blockIdx.x*4 + wvi) * 64;
    float asum=0.f, asq=0.f;
    float px=0.f, py=0.f, pz=0.f, xql=0.f;
    for (int e4 = 0; e4 < 16; ++e4){
        const int gb = base + e4*4;
        if ((gb & 15) == 0){
            const int n = gb >> 4;
            px=p32[n*3+0]; py=p32[n*3+1]; pz=p32[n*3+2];
            xql = xq[(size_t)n*64+lane];
        }
        int4 jj = *(const int4*)&idx_k[gb];
        int j[4] = { jj.x & IMASK, jj.y & IMASK, jj.z & IMASK, jj.w & IMASK };
        float kx[4], qx[4][3];
        #pragma unroll
        for (int u=0;u<4;++u){
            qx[u][0]=p32[j[u]*3+0]; qx[u][1]=p32[j[u]*3+1]; qx[u][2]=p32[j[u]*3+2];
            kx[u] = xk[(size_t)j[u]*64+lane];
        }
        #pragma unroll
        for (int u=0;u<4;++u){
            float rx = qx[u][0]-px, ry = qx[u][1]-py, rz = qx[u][2]-pz;
            float h0 = bb0 + rx*w00 + ry*w10 + rz*w20;
            float h1 = bb1 + rx*w01 + ry*w11 + rz*w21;
            float h2 = bb2 + rx*w02 + ry*w12 + rz*w22;
            float r0 = fmaxf(h0*sc0+sh0, 0.f), r1 = fmaxf(h1*sc1+sh1,0.f), r2 = fmaxf(h2*sc2+sh2,0.f);
            float pr = r0*wa + r1*wb + r2*wc + bpc;
            float rv = kx[u] - xql + pr;
            asum += rv; asq += rv*rv;
        }
    }
    __shared__ float red[4][128];
    red[wvi][lane] = asum; red[wvi][64+lane] = asq;
    __syncthreads();
    if (tid < 128) part2[(size_t)blockIdx.x*128 + tid] = red[0][tid]+red[1][tid]+red[2][tid]+red[3][tid];
}

// ---------------------------------------------------------------- BN3 stats over w (+ wbuf store)
__global__ __launch_bounds__(256) void k_wstats(
    const float* __restrict__ p32,
    const float* __restrict__ xq, const float* __restrict__ xk, const int* __restrict__ idx_k,
    const float* __restrict__ bn1aff, const float* __restrict__ prm,
    const float* __restrict__ bn2aff, float* __restrict__ wbuf, float* __restrict__ part3)
{
    __shared__ float4 PRW[64];
    __shared__ float2 SS2[64];
    __shared__ float4 W1A[64], W1B[64];
    const int tid = threadIdx.x;
    if (tid < 64){
        PRW[tid] = make_float4(prm[O_WP2+tid], prm[O_WP2+64+tid], prm[O_WP2+128+tid], prm[O_BP2+tid]);
        SS2[tid] = make_float2(bn2aff[tid], bn2aff[64+tid]);
        W1A[tid] = make_float4(prm[O_WW1+tid*8+0],prm[O_WW1+tid*8+1],prm[O_WW1+tid*8+2],prm[O_WW1+tid*8+3]);
        W1B[tid] = make_float4(prm[O_WW1+tid*8+4],prm[O_WW1+tid*8+5],prm[O_WW1+tid*8+6],prm[O_WW1+tid*8+7]);
    }
    __syncthreads();
    const int g = blockIdx.x*256 + tid;
    const int n = g >> 4;
    const int j = idx_k[g] & IMASK;
    const float w00=prm[O_WP1+0], w01=prm[O_WP1+1], w02=prm[O_WP1+2];
    const float w10=prm[O_WP1+3], w11=prm[O_WP1+4], w12=prm[O_WP1+5];
    const float w20=prm[O_WP1+6], w21=prm[O_WP1+7], w22=prm[O_WP1+8];
    const float bb0=prm[O_BP1+0], bb1=prm[O_BP1+1], bb2=prm[O_BP1+2];
    const float sc0=bn1aff[0], sc1=bn1aff[1], sc2=bn1aff[2];
    const float sh0=bn1aff[3], sh1=bn1aff[4], sh2=bn1aff[5];
    float rx = p32[j*3+0] - p32[n*3+0];
    float ry = p32[j*3+1] - p32[n*3+1];
    float rz = p32[j*3+2] - p32[n*3+2];
    float h0 = bb0 + rx*w00 + ry*w10 + rz*w20;
    float h1 = bb1 + rx*w01 + ry*w11 + rz*w21;
    float h2 = bb2 + rx*w02 + ry*w12 + rz*w22;
    float r0 = fmaxf(h0*sc0+sh0, 0.f), r1 = fmaxf(h1*sc1+sh1,0.f), r2 = fmaxf(h2*sc2+sh2,0.f);
    float wacc[8];
    #pragma unroll
    for (int i=0;i<8;++i) wacc[i] = prm[O_BW1+i];
    const float4* kr = (const float4*)(xk + (size_t)j*64);
    const float4* qr = (const float4*)(xq + (size_t)n*64);
    #pragma unroll
    for (int c4=0;c4<16;++c4){
        float4 kv = kr[c4], qv = qr[c4];
        float kvv[4] = {kv.x,kv.y,kv.z,kv.w};
        float qvv[4] = {qv.x,qv.y,qv.z,qv.w};
        #pragma unroll
        for (int d=0; d<4; ++d){
            int c = 4*c4 + d;
            float4 pw = PRW[c]; float2 ss = SS2[c];
            float pr = r0*pw.x + r1*pw.y + r2*pw.z + pw.w;
            float rr = kvv[d] - qvv[d] + pr;
            float y = fmaxf(rr*ss.x + ss.y, 0.f);
            float4 wA = W1A[c], wB = W1B[c];
            wacc[0]+=y*wA.x; wacc[1]+=y*wA.y; wacc[2]+=y*wA.z; wacc[3]+=y*wA.w;
            wacc[4]+=y*wB.x; wacc[5]+=y*wB.y; wacc[6]+=y*wB.z; wacc[7]+=y*wB.w;
        }
    }
    *(float4*)&wbuf[(size_t)g*8]   = make_float4(wacc[0],wacc[1],wacc[2],wacc[3]);
    *(float4*)&wbuf[(size_t)g*8+4] = make_float4(wacc[4],wacc[5],wacc[6],wacc[7]);
    float st[16];
    #pragma unroll
    for (int i=0;i<8;++i){ st[i]=wacc[i]; st[8+i]=wacc[i]*wacc[i]; }
    for (int off=32; off; off>>=1){
        #pragma unroll
        for (int k=0;k<16;++k) st[k] += __shfl_down(st[k], off);
    }
    __shared__ float red[4][16];
    const int lane = tid&63, wvi = tid>>6;
    if (lane==0){
        #pragma unroll
        for (int k=0;k<16;++k) red[wvi][k]=st[k];
    }
    __syncthreads();
    if (tid < 16) part3[(size_t)blockIdx.x*16 + tid] = red[0][tid]+red[1][tid]+red[2][tid]+red[3][tid];
}

// ---------------------------------------------------------------- final (reads wbuf; no shfl chain)
__global__ __launch_bounds__(256) void k_out(
    const float* __restrict__ p32, const float* __restrict__ xv,
    const int* __restrict__ idx_k, const int* __restrict__ idx_v,
    const float* __restrict__ bn1aff, const float* __restrict__ prm,
    const float* __restrict__ wbuf, const float* __restrict__ bn3aff,
    const int* __restrict__ flags, void* __restrict__ out)
{
    const int tid = threadIdx.x, lane = tid & 63, wvi = tid >> 6;
    const int n = blockIdx.x*4 + wvi;
    const int f32 = flags[0];
    const float w00=prm[O_WP1+0], w01=prm[O_WP1+1], w02=prm[O_WP1+2];
    const float w10=prm[O_WP1+3], w11=prm[O_WP1+4], w12=prm[O_WP1+5];
    const float w20=prm[O_WP1+6], w21=prm[O_WP1+7], w22=prm[O_WP1+8];
    const float bb0=prm[O_BP1+0], bb1=prm[O_BP1+1], bb2=prm[O_BP1+2];
    const float sc0=bn1aff[0], sc1=bn1aff[1], sc2=bn1aff[2];
    const float sh0=bn1aff[3], sh1=bn1aff[4], sh2=bn1aff[5];
    const float wa=prm[O_WP2+lane], wb=prm[O_WP2+64+lane], wc=prm[O_WP2+128+lane];
    const float bpc=prm[O_BP2+lane];
    const int i = lane & 7;
    float s3[8], t3[8], w2col[8];
    #pragma unroll
    for (int m=0;m<8;++m){
        s3[m]=bn3aff[m]; t3[m]=bn3aff[8+m];
        w2col[m]=prm[O_WW2+m*8+i];
    }
    const float bw2i = prm[O_BW2+i];
    const float px=p32[n*3+0], py=p32[n*3+1], pz=p32[n*3+2];
    float comb[16], wf[16];
    #pragma unroll
    for (int t=0;t<16;++t){
        const int g = n*16 + t;
        const int jk = idx_k[g] & IMASK;
        const int jv = idx_v[g] & IMASK;
        float rx=p32[jk*3+0]-px, ry=p32[jk*3+1]-py, rz=p32[jk*3+2]-pz;
        float h0=bb0+rx*w00+ry*w10+rz*w20;
        float h1=bb1+rx*w01+ry*w11+rz*w21;
        float h2=bb2+rx*w02+ry*w12+rz*w22;
        float r0=fmaxf(h0*sc0+sh0,0.f), r1=fmaxf(h1*sc1+sh1,0.f), r2=fmaxf(h2*sc2+sh2,0.f);
        float pr=r0*wa+r1*wb+r2*wc+bpc;
        float4 wA = *(const float4*)&wbuf[(size_t)g*8];
        float4 wB = *(const float4*)&wbuf[(size_t)g*8+4];
        float wm[8] = {wA.x,wA.y,wA.z,wA.w,wB.x,wB.y,wB.z,wB.w};
        float acc = bw2i;
        #pragma unroll
        for (int m=0;m<8;++m){
            float y3 = fmaxf(wm[m]*s3[m]+t3[m],0.f);
            acc += y3*w2col[m];
        }
        wf[t]=acc;
        comb[t]=xv[(size_t)jv*64+lane]+pr;
    }
    float mx = wf[0];
    #pragma unroll
    for (int t=1;t<16;++t) mx = fmaxf(mx, wf[t]);
    float ssum=0.f, osum=0.f;
    #pragma unroll
    for (int t=0;t<16;++t){ float e = __expf(wf[t]-mx); ssum += e; osum += e*comb[t]; }
    const float v = osum / ssum;
    if (f32) ((float*)out)[(size_t)n*64+lane] = v;
    else     ((bf16*)out)[(size_t)n*64+lane] = __float2bfloat16(v);
}

// ---------------------------------------------------------------- launcher
extern "C" void kernel_launch(void* const* d_in, const int* in_sizes, int n_in,
                              void* d_out, int out_size, void* d_ws, size_t ws_size,
                              hipStream_t stream)
{
    const void* p  = d_in[0];
    const void* x  = d_in[1];
    P20 prms;
    for (int i = 0; i < 20; ++i) prms.p[i] = d_in[3+i];

    // workspace layout (floats) — within the 48.08 MB proven footprint
    float* W = (float*)d_ws;
    float* xqf    = W + 0;
    float* xkf    = W + 2097152;
    float* xvf    = W + 4194304;
    float* sqk    = W + 6291456;
    float* sqv    = W + 6324224;
    int*   idx_k  = (int*)(W + 6356992);
    int*   idx_v  = (int*)(W + 6881280);
    float* p32    = W + 7405568;   // 98304
    float* prm    = W + 7503872;   // 13490 (+pad)
    float* part1  = W + 7517376;   // 512*6 (slack)
    float* part2  = W + 7529664;   // 2048*128
    float* part3  = W + 7791808;   // 2048*16
    float* bn1aff = W + 7824576;   // 16
    float* bn2aff = W + 7824592;   // 128
    float* bn3aff = W + 7824720;   // 16
    int*   flags  = (int*)(W + 7824736); // 2 (+pad to 16)
    // overlay region (4,194,304 floats): bf16 h/m planes (live: k_proj -> k_knn_part),
    // then wbuf (written k_wstats, read k_out) — disjoint lifetimes.
    unsigned* hkp = (unsigned*)(W + 7824752);             // 1,048,576 u32
    unsigned* mkp = (unsigned*)(W + 7824752 + 1048576);
    unsigned* hvp = (unsigned*)(W + 7824752 + 2097152);
    unsigned* mvp = (unsigned*)(W + 7824752 + 3145728);
    float* wbuf   = W + 7824752;   // 4,194,304

    const float invP = 1.f / (float)NPAIR;

    k_sniff<<<1,256,0,stream>>>(x, d_in[3], flags);
    k_conv_prm<<<(NPRM+255)/256,256,0,stream>>>(prms, flags, prm);
    k_conv_p<<<(NPTS*3+255)/256,256,0,stream>>>(p, flags, p32);
    k_proj<<<2048,256,0,stream>>>(x, flags, prm, xqf,xkf,xvf, sqk,sqv, hkp,mkp,hvp,mvp);
    k_knn_part<<<1024,256,0,stream>>>(xkf, xvf, hkp,mkp,hvp,mvp, sqk, sqv, idx_k, idx_v);
    k_bn1<<<512,64,0,stream>>>(idx_k, p32, prm, part1);
    k_bnred<<<1,256,0,stream>>>(part1, 512, 3, prm+O_GP, prm+O_BTP, bn1aff, invP);
    k_rstats<<<2048,256,0,stream>>>(p32, xqf, xkf, idx_k, bn1aff, prm, part2);
    k_bnred<<<1,256,0,stream>>>(part2, 2048, 64, prm+O_G1, prm+O_BT1, bn2aff, invP);
    k_wstats<<<2048,256,0,stream>>>(p32, xqf, xkf, idx_k, bn1aff, prm, bn2aff, wbuf, part3);
    k_bnred<<<1,256,0,stream>>>(part3, 2048, 8, prm+O_G2, prm+O_BT2, bn3aff, invP);
    k_out<<<8192,256,0,stream>>>(p32, xvf, idx_k, idx_v, bn1aff, prm,
                                 wbuf, bn3aff, flags, d_out);
}

// Round 6
// 797.598 us; speedup vs baseline: 1.8042x; 1.2010x over previous
//
#include <hip/hip_runtime.h>
#include <hip/hip_bf16.h>

typedef __hip_bfloat16 bf16;

#define NPTS  32768
#define NPB   4096
#define NPAIR (NPTS*16)
#define IMASK 32767
#define EPSB  1e-5f

// packed fp32 param-block offsets (floats)
#define O_WQ  0
#define O_BQ  4096
#define O_WK  4160
#define O_BK  8256
#define O_WV  8320
#define O_BV  12416
#define O_WP1 12480
#define O_BP1 12489
#define O_GP  12492
#define O_BTP 12495
#define O_WP2 12498
#define O_BP2 12690
#define O_G1  12754
#define O_BT1 12818
#define O_WW1 12882
#define O_BW1 13394
#define O_G2  13402
#define O_BT2 13410
#define O_WW2 13418
#define O_BW2 13482
#define NPRM  13490

__device__ __forceinline__ float b2f(bf16 v){ return __bfloat162float(v); }
__device__ __forceinline__ float u16f(unsigned short u){ return __uint_as_float(((unsigned)u)<<16); }
__device__ __forceinline__ float ldany(const void* p, long long i, int f32){
    return f32 ? ((const float*)p)[i] : b2f(((const bf16*)p)[i]);
}

// 2-way bf16 split: x ~= h + m (residual ~2^-17 |x|)
__device__ __forceinline__ void split2(float x, unsigned &h, unsigned &m){
    unsigned u  = __float_as_uint(x);
    unsigned hr = (u + 0x7FFFu + ((u>>16)&1u)) & 0xFFFF0000u;  // RTN-even bf16 (as fp32 bits)
    float xm = x - __uint_as_float(hr);                        // exact (Sterbenz)
    h = hr >> 16;
    m = __float_as_uint(xm) >> 16;                             // truncate
}

// ---------------------------------------------------------------- dtype sniff
__global__ __launch_bounds__(256) void k_sniff(const void* x, const void* wq, int* flags)
{
    __shared__ float red[2][4];
    const unsigned short* xu = (const unsigned short*)x;
    const unsigned short* wu = (const unsigned short*)wq;
    const int tid = threadIdx.x, lane = tid & 63, wvi = tid >> 6;
    float mx = fabsf(u16f(xu[tid]));
    float mw = fabsf(u16f(wu[tid]));
    for (int off = 32; off; off >>= 1){
        mx = fmaxf(mx, __shfl_down(mx, off));
        mw = fmaxf(mw, __shfl_down(mw, off));
    }
    if (lane == 0){ red[0][wvi] = mx; red[1][wvi] = mw; }
    __syncthreads();
    if (tid == 0){
        float ax = fmaxf(fmaxf(red[0][0], red[0][1]), fmaxf(red[0][2], red[0][3]));
        float aw = fmaxf(fmaxf(red[1][0], red[1][1]), fmaxf(red[1][2], red[1][3]));
        flags[0] = (ax > 1e6f) ? 1 : 0;
        flags[1] = (aw > 1e6f) ? 1 : 0;
    }
}

// ---------------------------------------------------------------- param canonicalization -> fp32 block
struct P20 { const void* p[20]; };

__global__ __launch_bounds__(256) void k_conv_prm(P20 t, const int* __restrict__ flags,
                                                  float* __restrict__ prm)
{
    const int i = blockIdx.x*256 + threadIdx.x;
    if (i >= NPRM) return;
    const int f = flags[1];
    const int sz[20] = {4096,64,4096,64,4096,64,9,3,3,3,192,64,64,64,512,8,8,8,64,8};
    int seg = 0, rem = i;
    while (rem >= sz[seg]){ rem -= sz[seg]; ++seg; }
    prm[i] = ldany(t.p[seg], rem, f);
}

__global__ __launch_bounds__(256) void k_conv_p(const void* __restrict__ p,
                                                const int* __restrict__ flags,
                                                float* __restrict__ p32)
{
    const int i = blockIdx.x*256 + threadIdx.x;
    if (i < NPTS*3) p32[i] = ldany(p, i, flags[0]);
}

// ---------------------------------------------------------------- projections (16 pts/block)
// Emits pre-swizzled packed bf16 h/m planes of xk and xv for the KNN MFMA prune.
__global__ __launch_bounds__(256) void k_proj(
    const void* __restrict__ x, const int* __restrict__ flags,
    const float* __restrict__ prm,
    float* __restrict__ xq, float* __restrict__ xk, float* __restrict__ xv,
    float* __restrict__ sqk, float* __restrict__ sqv,
    unsigned* __restrict__ hkp, unsigned* __restrict__ mkp,
    unsigned* __restrict__ hvp, unsigned* __restrict__ mvp)
{
    __shared__ float WQ[4096], WK[4096], WV[4096], BQ[64], BK[64], BV[64];
    const int tid = threadIdx.x;
    for (int i = tid; i < 4096; i += 256){
        WQ[i] = prm[O_WQ+i]; WK[i] = prm[O_WK+i]; WV[i] = prm[O_WV+i];
    }
    if (tid < 64){ BQ[tid]=prm[O_BQ+tid]; BK[tid]=prm[O_BK+tid]; BV[tid]=prm[O_BV+tid]; }
    const int f32 = flags[0];
    __syncthreads();
    const int lane = tid & 63, wvi = tid >> 6;
    const int ptbase = blockIdx.x*16 + wvi*4;
    for (int it = 0; it < 4; ++it){
        const int pt = ptbase + it;
        float xl = ldany(x, (long long)pt*64 + lane, f32);
        float aq = BQ[lane], ak = BK[lane], av = BV[lane];
        #pragma unroll
        for (int k = 0; k < 64; ++k){
            float xb = __shfl(xl, k);
            aq += xb*WQ[k*64+lane];
            ak += xb*WK[k*64+lane];
            av += xb*WV[k*64+lane];
        }
        xq[pt*64+lane]=aq; xk[pt*64+lane]=ak; xv[pt*64+lane]=av;
        unsigned hk16, mk16, hv16, mv16;
        split2(ak, hk16, mk16); split2(av, hv16, mv16);
        unsigned hkn = __shfl_down(hk16,1), mkn = __shfl_down(mk16,1);
        unsigned hvn = __shfl_down(hv16,1), mvn = __shfl_down(mv16,1);
        if (!(lane & 1)){
            const int u = lane >> 3, pos = u ^ (pt & 7);
            const size_t gi = (size_t)pt*32 + pos*4 + ((lane & 7) >> 1);
            hkp[gi] = hk16 | (hkn<<16);  mkp[gi] = mk16 | (mkn<<16);
            hvp[gi] = hv16 | (hvn<<16);  mvp[gi] = mv16 | (mvn<<16);
        }
        float s1 = ak*ak, s2 = av*av;
        for (int off=32; off; off>>=1){ s1 += __shfl_down(s1,off); s2 += __shfl_down(s2,off); }
        if (lane==0){ sqk[pt]=s1; sqv[pt]=s2; }
    }
}

// ---------------------------------------------------------------- KNN (MFMA prune + exact re-rank)
// grid 1024 (XCD-swizzled). Block: 64 queries vs ALL 4096 cands of the batch (64 chunks).
// Prune: 8-term h/m bf16 MFMA distance (round-4 proven). Top-20 per query DISTRIBUTED
//   5-sorted-entries per sub-lane (sub s holds global ranks 5s..5s+4). All 4 lanes process
//   the same hit sequence (combined mask, increasing c — identical set semantics to the
//   proven owner-lane code); each insertion = shfl prev-segment-last + local 5-deep
//   insert-with-drop == global 20-list shift, ~30 VALU instead of ~120, 64/64 lanes active.
// Tail: each lane exact-recomputes its 5 survivors (proven fmac sequence), sort-5,
//   LDS 4-way sorted merge -> top-16. Output == exact KNN (margin-4 containment).

using bfrag  = __attribute__((ext_vector_type(8))) short;   // 8 x bf16 (4 VGPRs)
using f32x4v = __attribute__((ext_vector_type(4))) float;   // MFMA accumulator

// swizzled LDS address (in shorts): row stride 64 shorts (128B), 16B units XOR'd by row&7
__device__ __forceinline__ int lds_sw(int row, int unit){
    return (row<<6) + (((unit ^ row) & 7)<<3);
}

__global__ __launch_bounds__(256, 4) void k_knn_part(
    const float* __restrict__ featk, const float* __restrict__ featv,
    const unsigned* __restrict__ hkp, const unsigned* __restrict__ mkp,
    const unsigned* __restrict__ hvp, const unsigned* __restrict__ mvp,
    const float* __restrict__ sqk, const float* __restrict__ sqv,
    int* __restrict__ idx_k, int* __restrict__ idx_v)
{
    __shared__ __attribute__((aligned(16))) unsigned char smem[34048];
    unsigned short* Ch = (unsigned short*)smem;                 // 8KB h-plane tile (swizzled)
    unsigned short* Cm = (unsigned short*)(smem + 8192);        // 8KB m-plane tile
    float* Dt  = (float*)(smem + 16384);                        // 64x68 dist tile (17408B)
    float* sqC = (float*)(smem + 16384 + 17408);                // 256B
    unsigned long long* Lbuf = (unsigned long long*)smem;       // tail overlay (256*6*8=12288B)

    const int tid = threadIdx.x;
    // XCD-aware swizzle: 1024 blocks = 8 XCDs x 128 contiguous logicals
    const int swz = ((int)blockIdx.x & 7) * 128 + ((int)blockIdx.x >> 3);
    const int kid = swz >> 9;
    const int bid = swz & 511;
    const float*    feat = kid ? featv : featk;
    const float*    sq   = kid ? sqv  : sqk;
    const unsigned* hpl  = kid ? hvp : hkp;
    const unsigned* mpl  = kid ? mvp : mkp;
    const int b  = bid >> 6;
    const int qt = bid & 63;
    const int q0 = b*NPB + qt*64;
    const int cb = b*NPB;

    const int lane = tid & 63, wv = tid >> 6;
    const int lq = lane & 15, lg = lane >> 4;        // MFMA fragment lane coords
    const int selq = (wv << 4) + (lane >> 2);        // selection row (0..63)
    const int sub  = lane & 3;
    const int owner = lane & ~3;
    const int row1 = tid >> 3, pos1 = tid & 7;       // staging: 16B-unit coords
    const int row2 = row1 + 32;

    // ---- Q fragments from planes (register-resident, 2 planes x 2 k-steps)
    bfrag qh[2], qm[2];
    {
        const int qr = q0 + (wv<<4) + lq;
        #pragma unroll
        for (int ks = 0; ks < 2; ++ks){
            const int u0 = ks*4 + lg;
            const int pos = u0 ^ (qr & 7);
            union { uint4 u; bfrag v; } ch, cm;
            ch.u = *(const uint4*)&hpl[(size_t)qr*32 + pos*4];
            cm.u = *(const uint4*)&mpl[(size_t)qr*32 + pos*4];
            qh[ks] = ch.v; qm[ks] = cm.v;
        }
    }

    // distributed top-20: 5 sorted entries per sub-lane (ranks sub*5 .. sub*5+4)
    float d5[5]; int i5[5];
    #pragma unroll
    for (int i=0;i<5;++i){ d5[i] = 3.4e38f; i5[i] = 0; }

    const unsigned* hrow1 = hpl + (size_t)cb*32 + (size_t)row1*32 + pos1*4;
    const unsigned* hrow2 = hpl + (size_t)cb*32 + (size_t)row2*32 + pos1*4;
    const unsigned* mrow1 = mpl + (size_t)cb*32 + (size_t)row1*32 + pos1*4;
    const unsigned* mrow2 = mpl + (size_t)cb*32 + (size_t)row2*32 + pos1*4;
    const int ldsoff1 = row1*64 + pos1*8, ldsoff2 = row2*64 + pos1*8;

    // prologue: stage chunk 0
    {
        uint4 a1 = *(const uint4*)hrow1; uint4 a2 = *(const uint4*)hrow2;
        uint4 b1 = *(const uint4*)mrow1; uint4 b2 = *(const uint4*)mrow2;
        *(uint4*)&Ch[ldsoff1] = a1; *(uint4*)&Ch[ldsoff2] = a2;
        *(uint4*)&Cm[ldsoff1] = b1; *(uint4*)&Cm[ldsoff2] = b2;
        if (tid < 64) sqC[tid] = sq[cb + tid];
    }
    __syncthreads();

    #define MFMA_PHASE() { \
        _Pragma("unroll") \
        for (int ct = 0; ct < 4; ++ct){ \
            const int cd = ct*16 + lq; \
            union { uint4 u; bfrag v; } bh0u, bh1u, bm0u, bm1u; \
            bh0u.u = *(const uint4*)&Ch[lds_sw(cd, lg)]; \
            bh1u.u = *(const uint4*)&Ch[lds_sw(cd, 4+lg)]; \
            bm0u.u = *(const uint4*)&Cm[lds_sw(cd, lg)]; \
            bm1u.u = *(const uint4*)&Cm[lds_sw(cd, 4+lg)]; \
            f32x4v a = {0.f, 0.f, 0.f, 0.f}; \
            a = __builtin_amdgcn_mfma_f32_16x16x32_bf16(qm[0], bm0u.v, a, 0, 0, 0); \
            a = __builtin_amdgcn_mfma_f32_16x16x32_bf16(qm[1], bm1u.v, a, 0, 0, 0); \
            a = __builtin_amdgcn_mfma_f32_16x16x32_bf16(qh[0], bm0u.v, a, 0, 0, 0); \
            a = __builtin_amdgcn_mfma_f32_16x16x32_bf16(qm[0], bh0u.v, a, 0, 0, 0); \
            a = __builtin_amdgcn_mfma_f32_16x16x32_bf16(qh[1], bm1u.v, a, 0, 0, 0); \
            a = __builtin_amdgcn_mfma_f32_16x16x32_bf16(qm[1], bh1u.v, a, 0, 0, 0); \
            a = __builtin_amdgcn_mfma_f32_16x16x32_bf16(qh[0], bh0u.v, a, 0, 0, 0); \
            a = __builtin_amdgcn_mfma_f32_16x16x32_bf16(qh[1], bh1u.v, a, 0, 0, 0); \
            const float sc = sqC[ct*16 + lq]; \
            _Pragma("unroll") \
            for (int r = 0; r < 4; ++r) \
                Dt[((wv<<4) + (lg<<2) + r)*68 + ct*16 + lq] = sc - 2.f*a[r]; \
        } }

    MFMA_PHASE()

    for (int chn = 0; chn < 64; ++chn){
        __syncthreads();   // Dt(chn) ready; Ch/Cm consumed by MFMA(chn)
        const bool more = (chn+1 < 64);
        uint4 a1, a2, b1, b2; float sqr = 0.f;
        if (more){
            const size_t co = (size_t)(chn+1)*2048;   // 64 rows * 32 u32
            a1 = *(const uint4*)(hrow1 + co); a2 = *(const uint4*)(hrow2 + co);
            b1 = *(const uint4*)(mrow1 + co); b2 = *(const uint4*)(mrow2 + co);
            if (tid < 64) sqr = sq[cb + (chn+1)*64 + tid];
        }
        // ---- cooperative distributed selection on Dt(chn)
        {
            float worst = __shfl(d5[4], owner+3);     // global rank-19 value
            unsigned m16 = 0;
            const int rowoff = selq*68 + sub*16;
            #pragma unroll
            for (int r = 0; r < 4; ++r){
                float4 v = *(const float4*)&Dt[rowoff + 4*r];
                m16 |= (v.x < worst ? 1u : 0u) << (4*r+0);
                m16 |= (v.y < worst ? 1u : 0u) << (4*r+1);
                m16 |= (v.z < worst ? 1u : 0u) << (4*r+2);
                m16 |= (v.w < worst ? 1u : 0u) << (4*r+3);
            }
            unsigned ma = __shfl(m16, owner+0), mb = __shfl(m16, owner+1);
            unsigned mc = __shfl(m16, owner+2), md = __shfl(m16, owner+3);
            unsigned long long m = (unsigned long long)ma
                                 | ((unsigned long long)mb << 16)
                                 | ((unsigned long long)mc << 32)
                                 | ((unsigned long long)md << 48);
            const int qrow = selq*68;
            const int c0 = cb + chn*64;
            const int prevlane = (lane - 1) & 63;
            while (m){
                int c = (int)__builtin_ctzll(m); m &= m - 1;
                float d = Dt[qrow + c];
                int gi = c0 + c;
                // incoming value for my segment: prev segment's (pre-insert) last, if it
                // beats d (i.e. insertion point lies before my segment)
                float pl = __shfl(d5[4], prevlane);
                int   pi = __shfl(i5[4], prevlane);
                bool takePrev = (sub != 0) && (pl > d);
                float v  = takePrev ? pl : d;
                int   vi = takePrev ? pi : gi;
                // local sorted insert with drop-last (== global 20-shift)
                #pragma unroll
                for (int i = 4; i >= 1; --i){
                    bool sh   = d5[i-1] > v;
                    bool here = !sh && (d5[i] > v);
                    d5[i] = sh ? d5[i-1] : (here ? v  : d5[i]);
                    i5[i] = sh ? i5[i-1] : (here ? vi : i5[i]);
                }
                bool h0 = d5[0] > v;
                d5[0] = h0 ? v  : d5[0];
                i5[0] = h0 ? vi : i5[0];
            }
        }
        if (more){
            *(uint4*)&Ch[ldsoff1] = a1; *(uint4*)&Ch[ldsoff2] = a2;
            *(uint4*)&Cm[ldsoff1] = b1; *(uint4*)&Cm[ldsoff2] = b2;
            if (tid < 64) sqC[tid] = sqr;
        }
        __syncthreads();   // planes(chn+1) staged; Dt free
        if (more) MFMA_PHASE()
    }
    #undef MFMA_PHASE

    // ---- tail: each lane exact-recomputes its own 5 survivors
    // exact VALU distance — IDENTICAL arithmetic to the proven round-3 code
    unsigned long long k5[5];
    {
        const float* qrow = feat + (size_t)(q0 + selq)*64;
        #pragma unroll
        for (int s = 0; s < 5; ++s){
            const int gi = i5[s];
            const float* crow = feat + (size_t)gi*64;
            float acc = 0.f;
            #pragma unroll
            for (int k4 = 0; k4 < 16; ++k4){
                float4 qv = *(const float4*)&qrow[4*k4];
                float4 cv = *(const float4*)&crow[4*k4];
                acc += qv.x*cv.x; acc += qv.y*cv.y; acc += qv.z*cv.z; acc += qv.w*cv.w;
            }
            float d = sq[gi] - 2.f*acc;
            unsigned ud = __float_as_uint(d);
            ud ^= (ud & 0x80000000u) ? 0xFFFFFFFFu : 0x80000000u;   // order-preserving map
            k5[s] = ((unsigned long long)ud << 32) | (unsigned)gi;  // (d, idx) lexicographic
        }
    }
    // static odd-even sort of 5 keys
    #pragma unroll
    for (int pass = 0; pass < 5; ++pass){
        #pragma unroll
        for (int i = (pass & 1); i + 1 < 5; i += 2){
            unsigned long long a = k5[i], bb = k5[i+1];
            bool sw = a > bb;
            k5[i]   = sw ? bb : a;
            k5[i+1] = sw ? a : bb;
        }
    }
    __syncthreads();   // smem reuse: planes/Dt dead
    #pragma unroll
    for (int j = 0; j < 5; ++j) Lbuf[(size_t)tid*6 + j] = k5[j];
    Lbuf[(size_t)tid*6 + 5] = ~0ull;   // sentinel
    __syncthreads();
    if (sub == 0){
        const unsigned long long* L0 = &Lbuf[(size_t)(tid+0)*6];
        const unsigned long long* L1 = &Lbuf[(size_t)(tid+1)*6];
        const unsigned long long* L2 = &Lbuf[(size_t)(tid+2)*6];
        const unsigned long long* L3 = &Lbuf[(size_t)(tid+3)*6];
        int p0 = 0, p1 = 0, p2 = 0, p3 = 0;
        int fi[16];
        #pragma unroll
        for (int o = 0; o < 16; ++o){
            unsigned long long b0 = L0[p0], b1v = L1[p1], b2v = L2[p2], b3v = L3[p3];
            unsigned long long m01 = (b0  < b1v) ? b0  : b1v;  int s01 = (b0  < b1v) ? 0 : 1;
            unsigned long long m23 = (b2v < b3v) ? b2v : b3v;  int s23 = (b2v < b3v) ? 2 : 3;
            unsigned long long mm  = (m01 < m23) ? m01 : m23;  int ss  = (m01 < m23) ? s01 : s23;
            fi[o] = (int)(unsigned)(mm & 0xFFFFFFFFull);
            if      (ss == 0) ++p0;
            else if (ss == 1) ++p1;
            else if (ss == 2) ++p2;
            else              ++p3;
        }
        int* idx_out = kid ? idx_v : idx_k;
        #pragma unroll
        for (int i4 = 0; i4 < 4; ++i4)
            *(int4*)&idx_out[(size_t)(q0+selq)*16 + 4*i4] =
                make_int4(fi[4*i4], fi[4*i4+1], fi[4*i4+2], fi[4*i4+3]);
    }
}

// ---------------------------------------------------------------- BN1 stats (reads idx_k)
__global__ __launch_bounds__(64) void k_bn1(
    const int* __restrict__ idx_k,
    const float* __restrict__ p32, const float* __restrict__ prm,
    float* __restrict__ part1)
{
    const int tid = threadIdx.x;
    const int blk = blockIdx.x;
    const size_t gq = (size_t)blk*64 + tid;
    int mi[16];
    #pragma unroll
    for (int o4 = 0; o4 < 4; ++o4){
        int4 v = *(const int4*)&idx_k[gq*16 + 4*o4];
        mi[4*o4]=v.x; mi[4*o4+1]=v.y; mi[4*o4+2]=v.z; mi[4*o4+3]=v.w;
    }
    const float w00=prm[O_WP1+0], w01=prm[O_WP1+1], w02=prm[O_WP1+2];
    const float w10=prm[O_WP1+3], w11=prm[O_WP1+4], w12=prm[O_WP1+5];
    const float w20=prm[O_WP1+6], w21=prm[O_WP1+7], w22=prm[O_WP1+8];
    const float bb0=prm[O_BP1+0], bb1=prm[O_BP1+1], bb2=prm[O_BP1+2];
    const float px=p32[gq*3+0], py=p32[gq*3+1], pz=p32[gq*3+2];
    float s0=0.f,s1=0.f,s2=0.f,t0=0.f,t1=0.f,t2=0.f;
    #pragma unroll
    for (int o = 0; o < 16; ++o){
        const int j = mi[o] & IMASK;
        float rx = p32[j*3+0]-px, ry = p32[j*3+1]-py, rz = p32[j*3+2]-pz;
        float h0 = bb0 + rx*w00 + ry*w10 + rz*w20;
        float h1 = bb1 + rx*w01 + ry*w11 + rz*w21;
        float h2 = bb2 + rx*w02 + ry*w12 + rz*w22;
        s0+=h0; s1+=h1; s2+=h2; t0+=h0*h0; t1+=h1*h1; t2+=h2*h2;
    }
    for (int off=32; off; off>>=1){
        s0+=__shfl_down(s0,off); s1+=__shfl_down(s1,off); s2+=__shfl_down(s2,off);
        t0+=__shfl_down(t0,off); t1+=__shfl_down(t1,off); t2+=__shfl_down(t2,off);
    }
    if (tid == 0){
        float* pp = part1 + blk*6;
        pp[0]=s0; pp[1]=s1; pp[2]=s2; pp[3]=t0; pp[4]=t1; pp[5]=t2;
    }
}

// ---------------------------------------------------------------- BN partial reduce -> affine
__global__ __launch_bounds__(256) void k_bnred(
    const float* __restrict__ part, int G, int C,
    const float* __restrict__ gamma, const float* __restrict__ beta,
    float* __restrict__ aff, float invCount)
{
    __shared__ float tot[128];
    const int tid = threadIdx.x, lane = tid & 63, wvi = tid >> 6;
    const int S = 2*C;
    for (int s = wvi; s < S; s += 4){
        float v = 0.f;
        for (int idx = lane; idx < G; idx += 64) v += part[(size_t)idx*S + s];
        for (int off=32; off; off>>=1) v += __shfl_down(v, off);
        if (lane == 0) tot[s] = v;
    }
    __syncthreads();
    if (tid < C){
        float mean = tot[tid]*invCount;
        float var  = fmaxf(tot[C+tid]*invCount - mean*mean, 0.f);
        float sc = gamma[tid] * rsqrtf(var + EPSB);
        aff[tid]   = sc;
        aff[C+tid] = beta[tid] - mean*sc;
    }
}

// ---------------------------------------------------------------- BN2 stats over r (unrolled x4)
__global__ __launch_bounds__(256) void k_rstats(
    const float* __restrict__ p32,
    const float* __restrict__ xq, const float* __restrict__ xk, const int* __restrict__ idx_k,
    const float* __restrict__ bn1aff, const float* __restrict__ prm,
    float* __restrict__ part2)
{
    const int tid = threadIdx.x, lane = tid & 63, wvi = tid >> 6;
    const float wa = prm[O_WP2+lane], wb = prm[O_WP2+64+lane], wc = prm[O_WP2+128+lane];
    const float bpc = prm[O_BP2+lane];
    const float w00=prm[O_WP1+0], w01=prm[O_WP1+1], w02=prm[O_WP1+2];
    const float w10=prm[O_WP1+3], w11=prm[O_WP1+4], w12=prm[O_WP1+5];
    const float w20=prm[O_WP1+6], w21=prm[O_WP1+7], w22=prm[O_WP1+8];
    const float bb0=prm[O_BP1+0], bb1=prm[O_BP1+1], bb2=prm[O_BP1+2];
    const float sc0=bn1aff[0], sc1=bn1aff[1], sc2=bn1aff[2];
    const float sh0=bn1aff[3], sh1=bn1aff[4], sh2=bn1aff[5];
    const int base = (blockIdx.x*4 + wvi) * 64;
    float asum=0.f, asq=0.f;
    float px=0.f, py=0.f, pz=0.f, xql=0.f;
    for (int e4 = 0; e4 < 16; ++e4){
        const int gb = base + e4*4;
        if ((gb & 15) == 0){
            const int n = gb >> 4;
            px=p32[n*3+0]; py=p32[n*3+1]; pz=p32[n*3+2];
            xql = xq[(size_t)n*64+lane];
        }
        int4 jj = *(const int4*)&idx_k[gb];
        int j[4] = { jj.x & IMASK, jj.y & IMASK, jj.z & IMASK, jj.w & IMASK };
        float kx[4], qx[4][3];
        #pragma unroll
        for (int u=0;u<4;++u){
            qx[u][0]=p32[j[u]*3+0]; qx[u][1]=p32[j[u]*3+1]; qx[u][2]=p32[j[u]*3+2];
            kx[u] = xk[(size_t)j[u]*64+lane];
        }
        #pragma unroll
        for (int u=0;u<4;++u){
            float rx = qx[u][0]-px, ry = qx[u][1]-py, rz = qx[u][2]-pz;
            float h0 = bb0 + rx*w00 + ry*w10 + rz*w20;
            float h1 = bb1 + rx*w01 + ry*w11 + rz*w21;
            float h2 = bb2 + rx*w02 + ry*w12 + rz*w22;
            float r0 = fmaxf(h0*sc0+sh0, 0.f), r1 = fmaxf(h1*sc1+sh1,0.f), r2 = fmaxf(h2*sc2+sh2,0.f);
            float pr = r0*wa + r1*wb + r2*wc + bpc;
            float rv = kx[u] - xql + pr;
            asum += rv; asq += rv*rv;
        }
    }
    __shared__ float red[4][128];
    red[wvi][lane] = asum; red[wvi][64+lane] = asq;
    __syncthreads();
    if (tid < 128) part2[(size_t)blockIdx.x*128 + tid] = red[0][tid]+red[1][tid]+red[2][tid]+red[3][tid];
}

// ---------------------------------------------------------------- BN3 stats over w (+ wbuf store)
__global__ __launch_bounds__(256) void k_wstats(
    const float* __restrict__ p32,
    const float* __restrict__ xq, const float* __restrict__ xk, const int* __restrict__ idx_k,
    const float* __restrict__ bn1aff, const float* __restrict__ prm,
    const float* __restrict__ bn2aff, float* __restrict__ wbuf, float* __restrict__ part3)
{
    __shared__ float4 PRW[64];
    __shared__ float2 SS2[64];
    __shared__ float4 W1A[64], W1B[64];
    const int tid = threadIdx.x;
    if (tid < 64){
        PRW[tid] = make_float4(prm[O_WP2+tid], prm[O_WP2+64+tid], prm[O_WP2+128+tid], prm[O_BP2+tid]);
        SS2[tid] = make_float2(bn2aff[tid], bn2aff[64+tid]);
        W1A[tid] = make_float4(prm[O_WW1+tid*8+0],prm[O_WW1+tid*8+1],prm[O_WW1+tid*8+2],prm[O_WW1+tid*8+3]);
        W1B[tid] = make_float4(prm[O_WW1+tid*8+4],prm[O_WW1+tid*8+5],prm[O_WW1+tid*8+6],prm[O_WW1+tid*8+7]);
    }
    __syncthreads();
    const int g = blockIdx.x*256 + tid;
    const int n = g >> 4;
    const int j = idx_k[g] & IMASK;
    const float w00=prm[O_WP1+0], w01=prm[O_WP1+1], w02=prm[O_WP1+2];
    const float w10=prm[O_WP1+3], w11=prm[O_WP1+4], w12=prm[O_WP1+5];
    const float w20=prm[O_WP1+6], w21=prm[O_WP1+7], w22=prm[O_WP1+8];
    const float bb0=prm[O_BP1+0], bb1=prm[O_BP1+1], bb2=prm[O_BP1+2];
    const float sc0=bn1aff[0], sc1=bn1aff[1], sc2=bn1aff[2];
    const float sh0=bn1aff[3], sh1=bn1aff[4], sh2=bn1aff[5];
    float rx = p32[j*3+0] - p32[n*3+0];
    float ry = p32[j*3+1] - p32[n*3+1];
    float rz = p32[j*3+2] - p32[n*3+2];
    float h0 = bb0 + rx*w00 + ry*w10 + rz*w20;
    float h1 = bb1 + rx*w01 + ry*w11 + rz*w21;
    float h2 = bb2 + rx*w02 + ry*w12 + rz*w22;
    float r0 = fmaxf(h0*sc0+sh0, 0.f), r1 = fmaxf(h1*sc1+sh1,0.f), r2 = fmaxf(h2*sc2+sh2,0.f);
    float wacc[8];
    #pragma unroll
    for (int i=0;i<8;++i) wacc[i] = prm[O_BW1+i];
    const float4* kr = (const float4*)(xk + (size_t)j*64);
    const float4* qr = (const float4*)(xq + (size_t)n*64);
    #pragma unroll
    for (int c4=0;c4<16;++c4){
        float4 kv = kr[c4], qv = qr[c4];
        float kvv[4] = {kv.x,kv.y,kv.z,kv.w};
        float qvv[4] = {qv.x,qv.y,qv.z,qv.w};
        #pragma unroll
        for (int d=0; d<4; ++d){
            int c = 4*c4 + d;
            float4 pw = PRW[c]; float2 ss = SS2[c];
            float pr = r0*pw.x + r1*pw.y + r2*pw.z + pw.w;
            float rr = kvv[d] - qvv[d] + pr;
            float y = fmaxf(rr*ss.x + ss.y, 0.f);
            float4 wA = W1A[c], wB = W1B[c];
            wacc[0]+=y*wA.x; wacc[1]+=y*wA.y; wacc[2]+=y*wA.z; wacc[3]+=y*wA.w;
            wacc[4]+=y*wB.x; wacc[5]+=y*wB.y; wacc[6]+=y*wB.z; wacc[7]+=y*wB.w;
        }
    }
    *(float4*)&wbuf[(size_t)g*8]   = make_float4(wacc[0],wacc[1],wacc[2],wacc[3]);
    *(float4*)&wbuf[(size_t)g*8+4] = make_float4(wacc[4],wacc[5],wacc[6],wacc[7]);
    float st[16];
    #pragma unroll
    for (int i=0;i<8;++i){ st[i]=wacc[i]; st[8+i]=wacc[i]*wacc[i]; }
    for (int off=32; off; off>>=1){
        #pragma unroll
        for (int k=0;k<16;++k) st[k] += __shfl_down(st[k], off);
    }
    __shared__ float red[4][16];
    const int lane = tid&63, wvi = tid>>6;
    if (lane==0){
        #pragma unroll
        for (int k=0;k<16;++k) red[wvi][k]=st[k];
    }
    __syncthreads();
    if (tid < 16) part3[(size_t)blockIdx.x*16 + tid] = red[0][tid]+red[1][tid]+red[2][tid]+red[3][tid];
}

// ---------------------------------------------------------------- final (reads wbuf; no shfl chain)
__global__ __launch_bounds__(256) void k_out(
    const float* __restrict__ p32, const float* __restrict__ xv,
    const int* __restrict__ idx_k, const int* __restrict__ idx_v,
    const float* __restrict__ bn1aff, const float* __restrict__ prm,
    const float* __restrict__ wbuf, const float* __restrict__ bn3aff,
    const int* __restrict__ flags, void* __restrict__ out)
{
    const int tid = threadIdx.x, lane = tid & 63, wvi = tid >> 6;
    const int n = blockIdx.x*4 + wvi;
    const int f32 = flags[0];
    const float w00=prm[O_WP1+0], w01=prm[O_WP1+1], w02=prm[O_WP1+2];
    const float w10=prm[O_WP1+3], w11=prm[O_WP1+4], w12=prm[O_WP1+5];
    const float w20=prm[O_WP1+6], w21=prm[O_WP1+7], w22=prm[O_WP1+8];
    const float bb0=prm[O_BP1+0], bb1=prm[O_BP1+1], bb2=prm[O_BP1+2];
    const float sc0=bn1aff[0], sc1=bn1aff[1], sc2=bn1aff[2];
    const float sh0=bn1aff[3], sh1=bn1aff[4], sh2=bn1aff[5];
    const float wa=prm[O_WP2+lane], wb=prm[O_WP2+64+lane], wc=prm[O_WP2+128+lane];
    const float bpc=prm[O_BP2+lane];
    const int i = lane & 7;
    float s3[8], t3[8], w2col[8];
    #pragma unroll
    for (int m=0;m<8;++m){
        s3[m]=bn3aff[m]; t3[m]=bn3aff[8+m];
        w2col[m]=prm[O_WW2+m*8+i];
    }
    const float bw2i = prm[O_BW2+i];
    const float px=p32[n*3+0], py=p32[n*3+1], pz=p32[n*3+2];
    float comb[16], wf[16];
    #pragma unroll
    for (int t=0;t<16;++t){
        const int g = n*16 + t;
        const int jk = idx_k[g] & IMASK;
        const int jv = idx_v[g] & IMASK;
        float rx=p32[jk*3+0]-px, ry=p32[jk*3+1]-py, rz=p32[jk*3+2]-pz;
        float h0=bb0+rx*w00+ry*w10+rz*w20;
        float h1=bb1+rx*w01+ry*w11+rz*w21;
        float h2=bb2+rx*w02+ry*w12+rz*w22;
        float r0=fmaxf(h0*sc0+sh0,0.f), r1=fmaxf(h1*sc1+sh1,0.f), r2=fmaxf(h2*sc2+sh2,0.f);
        float pr=r0*wa+r1*wb+r2*wc+bpc;
        float4 wA = *(const float4*)&wbuf[(size_t)g*8];
        float4 wB = *(const float4*)&wbuf[(size_t)g*8+4];
        float wm[8] = {wA.x,wA.y,wA.z,wA.w,wB.x,wB.y,wB.z,wB.w};
        float acc = bw2i;
        #pragma unroll
        for (int m=0;m<8;++m){
            float y3 = fmaxf(wm[m]*s3[m]+t3[m],0.f);
            acc += y3*w2col[m];
        }
        wf[t]=acc;
        comb[t]=xv[(size_t)jv*64+lane]+pr;
    }
    float mx = wf[0];
    #pragma unroll
    for (int t=1;t<16;++t) mx = fmaxf(mx, wf[t]);
    float ssum=0.f, osum=0.f;
    #pragma unroll
    for (int t=0;t<16;++t){ float e = __expf(wf[t]-mx); ssum += e; osum += e*comb[t]; }
    const float v = osum / ssum;
    if (f32) ((float*)out)[(size_t)n*64+lane] = v;
    else     ((bf16*)out)[(size_t)n*64+lane] = __float2bfloat16(v);
}

// ---------------------------------------------------------------- launcher
extern "C" void kernel_launch(void* const* d_in, const int* in_sizes, int n_in,
                              void* d_out, int out_size, void* d_ws, size_t ws_size,
                              hipStream_t stream)
{
    const void* p  = d_in[0];
    const void* x  = d_in[1];
    P20 prms;
    for (int i = 0; i < 20; ++i) prms.p[i] = d_in[3+i];

    // workspace layout (floats) — within the 48.08 MB proven footprint
    float* W = (float*)d_ws;
    float* xqf    = W + 0;
    float* xkf    = W + 2097152;
    float* xvf    = W + 4194304;
    float* sqk    = W + 6291456;
    float* sqv    = W + 6324224;
    int*   idx_k  = (int*)(W + 6356992);
    int*   idx_v  = (int*)(W + 6881280);
    float* p32    = W + 7405568;   // 98304
    float* prm    = W + 7503872;   // 13490 (+pad)
    float* part1  = W + 7517376;   // 512*6 (slack)
    float* part2  = W + 7529664;   // 2048*128
    float* part3  = W + 7791808;   // 2048*16
    float* bn1aff = W + 7824576;   // 16
    float* bn2aff = W + 7824592;   // 128
    float* bn3aff = W + 7824720;   // 16
    int*   flags  = (int*)(W + 7824736); // 2 (+pad to 16)
    // overlay region (4,194,304 floats): bf16 h/m planes (live: k_proj -> k_knn_part),
    // then wbuf (written k_wstats, read k_out) — disjoint lifetimes.
    unsigned* hkp = (unsigned*)(W + 7824752);             // 1,048,576 u32
    unsigned* mkp = (unsigned*)(W + 7824752 + 1048576);
    unsigned* hvp = (unsigned*)(W + 7824752 + 2097152);
    unsigned* mvp = (unsigned*)(W + 7824752 + 3145728);
    float* wbuf   = W + 7824752;   // 4,194,304

    const float invP = 1.f / (float)NPAIR;

    k_sniff<<<1,256,0,stream>>>(x, d_in[3], flags);
    k_conv_prm<<<(NPRM+255)/256,256,0,stream>>>(prms, flags, prm);
    k_conv_p<<<(NPTS*3+255)/256,256,0,stream>>>(p, flags, p32);
    k_proj<<<2048,256,0,stream>>>(x, flags, prm, xqf,xkf,xvf, sqk,sqv, hkp,mkp,hvp,mvp);
    k_knn_part<<<1024,256,0,stream>>>(xkf, xvf, hkp,mkp,hvp,mvp, sqk, sqv, idx_k, idx_v);
    k_bn1<<<512,64,0,stream>>>(idx_k, p32, prm, part1);
    k_bnred<<<1,256,0,stream>>>(part1, 512, 3, prm+O_GP, prm+O_BTP, bn1aff, invP);
    k_rstats<<<2048,256,0,stream>>>(p32, xqf, xkf, idx_k, bn1aff, prm, part2);
    k_bnred<<<1,256,0,stream>>>(part2, 2048, 64, prm+O_G1, prm+O_BT1, bn2aff, invP);
    k_wstats<<<2048,256,0,stream>>>(p32, xqf, xkf, idx_k, bn1aff, prm, bn2aff, wbuf, part3);
    k_bnred<<<1,256,0,stream>>>(part3, 2048, 8, prm+O_G2, prm+O_BT2, bn3aff, invP);
    k_out<<<8192,256,0,stream>>>(p32, xvf, idx_k, idx_v, bn1aff, prm,
                                 wbuf, bn3aff, flags, d_out);
}

// Round 7
// 609.455 us; speedup vs baseline: 2.3612x; 1.3087x over previous
//
#include <hip/hip_runtime.h>
#include <hip/hip_bf16.h>

typedef __hip_bfloat16 bf16;

#define NPTS  32768
#define NPB   4096
#define NPAIR (NPTS*16)
#define IMASK 32767
#define EPSB  1e-5f

// packed fp32 param-block offsets (floats)
#define O_WQ  0
#define O_BQ  4096
#define O_WK  4160
#define O_BK  8256
#define O_WV  8320
#define O_BV  12416
#define O_WP1 12480
#define O_BP1 12489
#define O_GP  12492
#define O_BTP 12495
#define O_WP2 12498
#define O_BP2 12690
#define O_G1  12754
#define O_BT1 12818
#define O_WW1 12882
#define O_BW1 13394
#define O_G2  13402
#define O_BT2 13410
#define O_WW2 13418
#define O_BW2 13482
#define NPRM  13490

__device__ __forceinline__ float b2f(bf16 v){ return __bfloat162float(v); }
__device__ __forceinline__ float u16f(unsigned short u){ return __uint_as_float(((unsigned)u)<<16); }
__device__ __forceinline__ float ldany(const void* p, long long i, int f32){
    return f32 ? ((const float*)p)[i] : b2f(((const bf16*)p)[i]);
}

// 2-way bf16 split: x ~= h + m (residual ~2^-17 |x|)
__device__ __forceinline__ void split2(float x, unsigned &h, unsigned &m){
    unsigned u  = __float_as_uint(x);
    unsigned hr = (u + 0x7FFFu + ((u>>16)&1u)) & 0xFFFF0000u;  // RTN-even bf16 (as fp32 bits)
    float xm = x - __uint_as_float(hr);                        // exact (Sterbenz)
    h = hr >> 16;
    m = __float_as_uint(xm) >> 16;                             // truncate
}

// ---------------------------------------------------------------- dtype sniff
__global__ __launch_bounds__(256) void k_sniff(const void* x, const void* wq, int* flags)
{
    __shared__ float red[2][4];
    const unsigned short* xu = (const unsigned short*)x;
    const unsigned short* wu = (const unsigned short*)wq;
    const int tid = threadIdx.x, lane = tid & 63, wvi = tid >> 6;
    float mx = fabsf(u16f(xu[tid]));
    float mw = fabsf(u16f(wu[tid]));
    for (int off = 32; off; off >>= 1){
        mx = fmaxf(mx, __shfl_down(mx, off));
        mw = fmaxf(mw, __shfl_down(mw, off));
    }
    if (lane == 0){ red[0][wvi] = mx; red[1][wvi] = mw; }
    __syncthreads();
    if (tid == 0){
        float ax = fmaxf(fmaxf(red[0][0], red[0][1]), fmaxf(red[0][2], red[0][3]));
        float aw = fmaxf(fmaxf(red[1][0], red[1][1]), fmaxf(red[1][2], red[1][3]));
        flags[0] = (ax > 1e6f) ? 1 : 0;
        flags[1] = (aw > 1e6f) ? 1 : 0;
    }
}

// ---------------------------------------------------------------- param + p canonicalization (merged)
struct P20 { const void* p[20]; };

__global__ __launch_bounds__(256) void k_conv(P20 t, const void* __restrict__ p,
                                              const int* __restrict__ flags,
                                              float* __restrict__ prm, float* __restrict__ p32)
{
    const int i = blockIdx.x*256 + threadIdx.x;
    if (i < NPRM){
        const int f = flags[1];
        const int sz[20] = {4096,64,4096,64,4096,64,9,3,3,3,192,64,64,64,512,8,8,8,64,8};
        int seg = 0, rem = i;
        while (rem >= sz[seg]){ rem -= sz[seg]; ++seg; }
        prm[i] = ldany(t.p[seg], rem, f);
    } else {
        const int j = i - NPRM;
        if (j < NPTS*3) p32[j] = ldany(p, j, flags[0]);
    }
}

// ---------------------------------------------------------------- projections (16 pts/block)
// Emits pre-swizzled packed bf16 h/m planes of xk and xv for the KNN MFMA prune.
__global__ __launch_bounds__(256) void k_proj(
    const void* __restrict__ x, const int* __restrict__ flags,
    const float* __restrict__ prm,
    float* __restrict__ xq, float* __restrict__ xk, float* __restrict__ xv,
    float* __restrict__ sqk, float* __restrict__ sqv,
    unsigned* __restrict__ hkp, unsigned* __restrict__ mkp,
    unsigned* __restrict__ hvp, unsigned* __restrict__ mvp)
{
    __shared__ float WQ[4096], WK[4096], WV[4096], BQ[64], BK[64], BV[64];
    const int tid = threadIdx.x;
    for (int i = tid; i < 4096; i += 256){
        WQ[i] = prm[O_WQ+i]; WK[i] = prm[O_WK+i]; WV[i] = prm[O_WV+i];
    }
    if (tid < 64){ BQ[tid]=prm[O_BQ+tid]; BK[tid]=prm[O_BK+tid]; BV[tid]=prm[O_BV+tid]; }
    const int f32 = flags[0];
    __syncthreads();
    const int lane = tid & 63, wvi = tid >> 6;
    const int ptbase = blockIdx.x*16 + wvi*4;
    for (int it = 0; it < 4; ++it){
        const int pt = ptbase + it;
        float xl = ldany(x, (long long)pt*64 + lane, f32);
        float aq = BQ[lane], ak = BK[lane], av = BV[lane];
        #pragma unroll
        for (int k = 0; k < 64; ++k){
            float xb = __shfl(xl, k);
            aq += xb*WQ[k*64+lane];
            ak += xb*WK[k*64+lane];
            av += xb*WV[k*64+lane];
        }
        xq[pt*64+lane]=aq; xk[pt*64+lane]=ak; xv[pt*64+lane]=av;
        unsigned hk16, mk16, hv16, mv16;
        split2(ak, hk16, mk16); split2(av, hv16, mv16);
        unsigned hkn = __shfl_down(hk16,1), mkn = __shfl_down(mk16,1);
        unsigned hvn = __shfl_down(hv16,1), mvn = __shfl_down(mv16,1);
        if (!(lane & 1)){
            const int u = lane >> 3, pos = u ^ (pt & 7);
            const size_t gi = (size_t)pt*32 + pos*4 + ((lane & 7) >> 1);
            hkp[gi] = hk16 | (hkn<<16);  mkp[gi] = mk16 | (mkn<<16);
            hvp[gi] = hv16 | (hvn<<16);  mvp[gi] = mv16 | (mvn<<16);
        }
        float s1 = ak*ak, s2 = av*av;
        for (int off=32; off; off>>=1){ s1 += __shfl_down(s1,off); s2 += __shfl_down(s2,off); }
        if (lane==0){ sqk[pt]=s1; sqv[pt]=s2; }
    }
}

// ---------------------------------------------------------------- KNN (MFMA prune + exact re-rank + fused BN1)
// grid 1024 (XCD-swizzled). Block: 64 queries vs ALL 4096 cands of the batch (64 chunks).
// Prune: 8-term h/m bf16 MFMA distance. Distributed top-20 (5 sorted/sub-lane),
// cooperative insert (round-6 proven). Tail: per-lane exact recompute (proven fmac
// sequence), sort-5, LDS 4-way merge -> top-16. kid==0 blocks also emit BN1 partial
// stats for their 64 queries (transposed part1[6][512]) — replaces the k_bn1 dispatch.

using bfrag  = __attribute__((ext_vector_type(8))) short;   // 8 x bf16 (4 VGPRs)
using f32x4v = __attribute__((ext_vector_type(4))) float;   // MFMA accumulator

// swizzled LDS address (in shorts): row stride 64 shorts (128B), 16B units XOR'd by row&7
__device__ __forceinline__ int lds_sw(int row, int unit){
    return (row<<6) + (((unit ^ row) & 7)<<3);
}

__global__ __launch_bounds__(256, 4) void k_knn_part(
    const float* __restrict__ featk, const float* __restrict__ featv,
    const unsigned* __restrict__ hkp, const unsigned* __restrict__ mkp,
    const unsigned* __restrict__ hvp, const unsigned* __restrict__ mvp,
    const float* __restrict__ sqk, const float* __restrict__ sqv,
    const float* __restrict__ p32, const float* __restrict__ prm,
    int* __restrict__ idx_k, int* __restrict__ idx_v,
    float* __restrict__ part1)
{
    __shared__ __attribute__((aligned(16))) unsigned char smem[34048];
    __shared__ float bn1red[4][6];
    unsigned short* Ch = (unsigned short*)smem;                 // 8KB h-plane tile (swizzled)
    unsigned short* Cm = (unsigned short*)(smem + 8192);        // 8KB m-plane tile
    float* Dt  = (float*)(smem + 16384);                        // 64x68 dist tile (17408B)
    float* sqC = (float*)(smem + 16384 + 17408);                // 256B
    unsigned long long* Lbuf = (unsigned long long*)smem;       // tail overlay (256*6*8=12288B)

    const int tid = threadIdx.x;
    // XCD-aware swizzle: 1024 blocks = 8 XCDs x 128 contiguous logicals
    const int swz = ((int)blockIdx.x & 7) * 128 + ((int)blockIdx.x >> 3);
    const int kid = swz >> 9;
    const int bid = swz & 511;
    const float*    feat = kid ? featv : featk;
    const float*    sq   = kid ? sqv  : sqk;
    const unsigned* hpl  = kid ? hvp : hkp;
    const unsigned* mpl  = kid ? mvp : mkp;
    const int b  = bid >> 6;
    const int qt = bid & 63;
    const int q0 = b*NPB + qt*64;
    const int cb = b*NPB;

    const int lane = tid & 63, wv = tid >> 6;
    const int lq = lane & 15, lg = lane >> 4;        // MFMA fragment lane coords
    const int selq = (wv << 4) + (lane >> 2);        // selection row (0..63)
    const int sub  = lane & 3;
    const int owner = lane & ~3;
    const int row1 = tid >> 3, pos1 = tid & 7;       // staging: 16B-unit coords
    const int row2 = row1 + 32;

    // ---- Q fragments from planes (register-resident, 2 planes x 2 k-steps)
    bfrag qh[2], qm[2];
    {
        const int qr = q0 + (wv<<4) + lq;
        #pragma unroll
        for (int ks = 0; ks < 2; ++ks){
            const int u0 = ks*4 + lg;
            const int pos = u0 ^ (qr & 7);
            union { uint4 u; bfrag v; } ch, cm;
            ch.u = *(const uint4*)&hpl[(size_t)qr*32 + pos*4];
            cm.u = *(const uint4*)&mpl[(size_t)qr*32 + pos*4];
            qh[ks] = ch.v; qm[ks] = cm.v;
        }
    }

    // distributed top-20: 5 sorted entries per sub-lane (ranks sub*5 .. sub*5+4)
    float d5[5]; int i5[5];
    #pragma unroll
    for (int i=0;i<5;++i){ d5[i] = 3.4e38f; i5[i] = 0; }

    const unsigned* hrow1 = hpl + (size_t)cb*32 + (size_t)row1*32 + pos1*4;
    const unsigned* hrow2 = hpl + (size_t)cb*32 + (size_t)row2*32 + pos1*4;
    const unsigned* mrow1 = mpl + (size_t)cb*32 + (size_t)row1*32 + pos1*4;
    const unsigned* mrow2 = mpl + (size_t)cb*32 + (size_t)row2*32 + pos1*4;
    const int ldsoff1 = row1*64 + pos1*8, ldsoff2 = row2*64 + pos1*8;

    // prologue: stage chunk 0
    {
        uint4 a1 = *(const uint4*)hrow1; uint4 a2 = *(const uint4*)hrow2;
        uint4 b1 = *(const uint4*)mrow1; uint4 b2 = *(const uint4*)mrow2;
        *(uint4*)&Ch[ldsoff1] = a1; *(uint4*)&Ch[ldsoff2] = a2;
        *(uint4*)&Cm[ldsoff1] = b1; *(uint4*)&Cm[ldsoff2] = b2;
        if (tid < 64) sqC[tid] = sq[cb + tid];
    }
    __syncthreads();

    #define MFMA_PHASE() { \
        _Pragma("unroll") \
        for (int ct = 0; ct < 4; ++ct){ \
            const int cd = ct*16 + lq; \
            union { uint4 u; bfrag v; } bh0u, bh1u, bm0u, bm1u; \
            bh0u.u = *(const uint4*)&Ch[lds_sw(cd, lg)]; \
            bh1u.u = *(const uint4*)&Ch[lds_sw(cd, 4+lg)]; \
            bm0u.u = *(const uint4*)&Cm[lds_sw(cd, lg)]; \
            bm1u.u = *(const uint4*)&Cm[lds_sw(cd, 4+lg)]; \
            f32x4v a = {0.f, 0.f, 0.f, 0.f}; \
            a = __builtin_amdgcn_mfma_f32_16x16x32_bf16(qm[0], bm0u.v, a, 0, 0, 0); \
            a = __builtin_amdgcn_mfma_f32_16x16x32_bf16(qm[1], bm1u.v, a, 0, 0, 0); \
            a = __builtin_amdgcn_mfma_f32_16x16x32_bf16(qh[0], bm0u.v, a, 0, 0, 0); \
            a = __builtin_amdgcn_mfma_f32_16x16x32_bf16(qm[0], bh0u.v, a, 0, 0, 0); \
            a = __builtin_amdgcn_mfma_f32_16x16x32_bf16(qh[1], bm1u.v, a, 0, 0, 0); \
            a = __builtin_amdgcn_mfma_f32_16x16x32_bf16(qm[1], bh1u.v, a, 0, 0, 0); \
            a = __builtin_amdgcn_mfma_f32_16x16x32_bf16(qh[0], bh0u.v, a, 0, 0, 0); \
            a = __builtin_amdgcn_mfma_f32_16x16x32_bf16(qh[1], bh1u.v, a, 0, 0, 0); \
            const float sc = sqC[ct*16 + lq]; \
            _Pragma("unroll") \
            for (int r = 0; r < 4; ++r) \
                Dt[((wv<<4) + (lg<<2) + r)*68 + ct*16 + lq] = sc - 2.f*a[r]; \
        } }

    MFMA_PHASE()

    for (int chn = 0; chn < 64; ++chn){
        __syncthreads();   // Dt(chn) ready; Ch/Cm consumed by MFMA(chn)
        const bool more = (chn+1 < 64);
        uint4 a1, a2, b1, b2; float sqr = 0.f;
        if (more){
            const size_t co = (size_t)(chn+1)*2048;   // 64 rows * 32 u32
            a1 = *(const uint4*)(hrow1 + co); a2 = *(const uint4*)(hrow2 + co);
            b1 = *(const uint4*)(mrow1 + co); b2 = *(const uint4*)(mrow2 + co);
            if (tid < 64) sqr = sq[cb + (chn+1)*64 + tid];
        }
        // ---- cooperative distributed selection on Dt(chn)
        {
            float worst = __shfl(d5[4], owner+3);     // global rank-19 value
            unsigned m16 = 0;
            const int rowoff = selq*68 + sub*16;
            #pragma unroll
            for (int r = 0; r < 4; ++r){
                float4 v = *(const float4*)&Dt[rowoff + 4*r];
                m16 |= (v.x < worst ? 1u : 0u) << (4*r+0);
                m16 |= (v.y < worst ? 1u : 0u) << (4*r+1);
                m16 |= (v.z < worst ? 1u : 0u) << (4*r+2);
                m16 |= (v.w < worst ? 1u : 0u) << (4*r+3);
            }
            unsigned ma = __shfl(m16, owner+0), mb = __shfl(m16, owner+1);
            unsigned mc = __shfl(m16, owner+2), md = __shfl(m16, owner+3);
            unsigned long long m = (unsigned long long)ma
                                 | ((unsigned long long)mb << 16)
                                 | ((unsigned long long)mc << 32)
                                 | ((unsigned long long)md << 48);
            const int qrow = selq*68;
            const int c0 = cb + chn*64;
            const int prevlane = (lane - 1) & 63;
            while (m){
                int c = (int)__builtin_ctzll(m); m &= m - 1;
                float d = Dt[qrow + c];
                int gi = c0 + c;
                float pl = __shfl(d5[4], prevlane);
                int   pi = __shfl(i5[4], prevlane);
                bool takePrev = (sub != 0) && (pl > d);
                float v  = takePrev ? pl : d;
                int   vi = takePrev ? pi : gi;
                #pragma unroll
                for (int i = 4; i >= 1; --i){
                    bool sh   = d5[i-1] > v;
                    bool here = !sh && (d5[i] > v);
                    d5[i] = sh ? d5[i-1] : (here ? v  : d5[i]);
                    i5[i] = sh ? i5[i-1] : (here ? vi : i5[i]);
                }
                bool h0 = d5[0] > v;
                d5[0] = h0 ? v  : d5[0];
                i5[0] = h0 ? vi : i5[0];
            }
        }
        if (more){
            *(uint4*)&Ch[ldsoff1] = a1; *(uint4*)&Ch[ldsoff2] = a2;
            *(uint4*)&Cm[ldsoff1] = b1; *(uint4*)&Cm[ldsoff2] = b2;
            if (tid < 64) sqC[tid] = sqr;
        }
        __syncthreads();   // planes(chn+1) staged; Dt free
        if (more) MFMA_PHASE()
    }
    #undef MFMA_PHASE

    // ---- tail: each lane exact-recomputes its own 5 survivors
    // exact VALU distance — IDENTICAL arithmetic to the proven round-3 code
    unsigned long long k5[5];
    {
        const float* qrow = feat + (size_t)(q0 + selq)*64;
        #pragma unroll
        for (int s = 0; s < 5; ++s){
            const int gi = i5[s];
            const float* crow = feat + (size_t)gi*64;
            float acc = 0.f;
            #pragma unroll
            for (int k4 = 0; k4 < 16; ++k4){
                float4 qv = *(const float4*)&qrow[4*k4];
                float4 cv = *(const float4*)&crow[4*k4];
                acc += qv.x*cv.x; acc += qv.y*cv.y; acc += qv.z*cv.z; acc += qv.w*cv.w;
            }
            float d = sq[gi] - 2.f*acc;
            unsigned ud = __float_as_uint(d);
            ud ^= (ud & 0x80000000u) ? 0xFFFFFFFFu : 0x80000000u;   // order-preserving map
            k5[s] = ((unsigned long long)ud << 32) | (unsigned)gi;  // (d, idx) lexicographic
        }
    }
    // static odd-even sort of 5 keys
    #pragma unroll
    for (int pass = 0; pass < 5; ++pass){
        #pragma unroll
        for (int i = (pass & 1); i + 1 < 5; i += 2){
            unsigned long long a = k5[i], bb = k5[i+1];
            bool sw = a > bb;
            k5[i]   = sw ? bb : a;
            k5[i+1] = sw ? a : bb;
        }
    }
    __syncthreads();   // smem reuse: planes/Dt dead
    #pragma unroll
    for (int j = 0; j < 5; ++j) Lbuf[(size_t)tid*6 + j] = k5[j];
    Lbuf[(size_t)tid*6 + 5] = ~0ull;   // sentinel
    __syncthreads();
    int fi[16];
    #pragma unroll
    for (int i = 0; i < 16; ++i) fi[i] = 0;
    if (sub == 0){
        const unsigned long long* L0 = &Lbuf[(size_t)(tid+0)*6];
        const unsigned long long* L1 = &Lbuf[(size_t)(tid+1)*6];
        const unsigned long long* L2 = &Lbuf[(size_t)(tid+2)*6];
        const unsigned long long* L3 = &Lbuf[(size_t)(tid+3)*6];
        int p0 = 0, p1 = 0, p2 = 0, p3 = 0;
        #pragma unroll
        for (int o = 0; o < 16; ++o){
            unsigned long long b0 = L0[p0], b1v = L1[p1], b2v = L2[p2], b3v = L3[p3];
            unsigned long long m01 = (b0  < b1v) ? b0  : b1v;  int s01 = (b0  < b1v) ? 0 : 1;
            unsigned long long m23 = (b2v < b3v) ? b2v : b3v;  int s23 = (b2v < b3v) ? 2 : 3;
            unsigned long long mm  = (m01 < m23) ? m01 : m23;  int ss  = (m01 < m23) ? s01 : s23;
            fi[o] = (int)(unsigned)(mm & 0xFFFFFFFFull);
            if      (ss == 0) ++p0;
            else if (ss == 1) ++p1;
            else if (ss == 2) ++p2;
            else              ++p3;
        }
        int* idx_out = kid ? idx_v : idx_k;
        #pragma unroll
        for (int i4 = 0; i4 < 4; ++i4)
            *(int4*)&idx_out[(size_t)(q0+selq)*16 + 4*i4] =
                make_int4(fi[4*i4], fi[4*i4+1], fi[4*i4+2], fi[4*i4+3]);
    }

    // ---- fused BN1 partial stats (kid==0 blocks): h = p_rel @ wp1 + bp1 over block's
    // 64 queries x 16 neighbors; 4 neighbors per sub-lane; full-wave butterfly reduce.
    if (kid == 0){
        const float w00=prm[O_WP1+0], w01=prm[O_WP1+1], w02=prm[O_WP1+2];
        const float w10=prm[O_WP1+3], w11=prm[O_WP1+4], w12=prm[O_WP1+5];
        const float w20=prm[O_WP1+6], w21=prm[O_WP1+7], w22=prm[O_WP1+8];
        const float bb0=prm[O_BP1+0], bb1=prm[O_BP1+1], bb2=prm[O_BP1+2];
        const size_t gq = (size_t)(q0 + selq);
        const float px=p32[gq*3+0], py=p32[gq*3+1], pz=p32[gq*3+2];
        float s0=0.f,s1=0.f,s2=0.f,t0=0.f,t1=0.f,t2=0.f;
        #pragma unroll
        for (int o = 0; o < 16; ++o){
            int gi = __shfl(fi[o], owner);
            if ((o & 3) == sub){
                const int j = gi & IMASK;
                float rx = p32[j*3+0]-px, ry = p32[j*3+1]-py, rz = p32[j*3+2]-pz;
                float h0 = bb0 + rx*w00 + ry*w10 + rz*w20;
                float h1 = bb1 + rx*w01 + ry*w11 + rz*w21;
                float h2 = bb2 + rx*w02 + ry*w12 + rz*w22;
                s0+=h0; s1+=h1; s2+=h2; t0+=h0*h0; t1+=h1*h1; t2+=h2*h2;
            }
        }
        #pragma unroll
        for (int off = 1; off < 64; off <<= 1){
            s0+=__shfl_down(s0,off); s1+=__shfl_down(s1,off); s2+=__shfl_down(s2,off);
            t0+=__shfl_down(t0,off); t1+=__shfl_down(t1,off); t2+=__shfl_down(t2,off);
        }
        if (lane == 0){
            bn1red[wv][0]=s0; bn1red[wv][1]=s1; bn1red[wv][2]=s2;
            bn1red[wv][3]=t0; bn1red[wv][4]=t1; bn1red[wv][5]=t2;
        }
        __syncthreads();
        if (tid < 6)
            part1[(size_t)tid*512 + bid] =
                bn1red[0][tid]+bn1red[1][tid]+bn1red[2][tid]+bn1red[3][tid];
    }
}

// ---------------------------------------------------------------- BN reduce (parallel, transposed part[S][G])
// grid = C blocks; block c reduces channels c (sum) and C+c (sumsq), writes aff.
__global__ __launch_bounds__(256) void k_bnred_par(
    const float* __restrict__ part, int G, int C,
    const float* __restrict__ gamma, const float* __restrict__ beta,
    float* __restrict__ aff, float invCount)
{
    __shared__ float rs[4], rq[4];
    const int c = blockIdx.x;
    const int tid = threadIdx.x;
    float s = 0.f, q = 0.f;
    for (int g = tid; g < G; g += 256){
        s += part[(size_t)c*G + g];
        q += part[(size_t)(C+c)*G + g];
    }
    for (int off=32; off; off>>=1){ s += __shfl_down(s,off); q += __shfl_down(q,off); }
    if ((tid & 63) == 0){ rs[tid>>6] = s; rq[tid>>6] = q; }
    __syncthreads();
    if (tid == 0){
        float S = rs[0]+rs[1]+rs[2]+rs[3], Q = rq[0]+rq[1]+rq[2]+rq[3];
        float mean = S*invCount;
        float var  = fmaxf(Q*invCount - mean*mean, 0.f);
        float sc = gamma[c] * rsqrtf(var + EPSB);
        aff[c]   = sc;
        aff[C+c] = beta[c] - mean*sc;
    }
}

// ---------------------------------------------------------------- BN2 stats over r (unrolled x4)
__global__ __launch_bounds__(256) void k_rstats(
    const float* __restrict__ p32,
    const float* __restrict__ xq, const float* __restrict__ xk, const int* __restrict__ idx_k,
    const float* __restrict__ bn1aff, const float* __restrict__ prm,
    float* __restrict__ part2)
{
    const int tid = threadIdx.x, lane = tid & 63, wvi = tid >> 6;
    const float wa = prm[O_WP2+lane], wb = prm[O_WP2+64+lane], wc = prm[O_WP2+128+lane];
    const float bpc = prm[O_BP2+lane];
    const float w00=prm[O_WP1+0], w01=prm[O_WP1+1], w02=prm[O_WP1+2];
    const float w10=prm[O_WP1+3], w11=prm[O_WP1+4], w12=prm[O_WP1+5];
    const float w20=prm[O_WP1+6], w21=prm[O_WP1+7], w22=prm[O_WP1+8];
    const float bb0=prm[O_BP1+0], bb1=prm[O_BP1+1], bb2=prm[O_BP1+2];
    const float sc0=bn1aff[0], sc1=bn1aff[1], sc2=bn1aff[2];
    const float sh0=bn1aff[3], sh1=bn1aff[4], sh2=bn1aff[5];
    const int base = (blockIdx.x*4 + wvi) * 64;
    float asum=0.f, asq=0.f;
    float px=0.f, py=0.f, pz=0.f, xql=0.f;
    for (int e4 = 0; e4 < 16; ++e4){
        const int gb = base + e4*4;
        if ((gb & 15) == 0){
            const int n = gb >> 4;
            px=p32[n*3+0]; py=p32[n*3+1]; pz=p32[n*3+2];
            xql = xq[(size_t)n*64+lane];
        }
        int4 jj = *(const int4*)&idx_k[gb];
        int j[4] = { jj.x & IMASK, jj.y & IMASK, jj.z & IMASK, jj.w & IMASK };
        float kx[4], qx[4][3];
        #pragma unroll
        for (int u=0;u<4;++u){
            qx[u][0]=p32[j[u]*3+0]; qx[u][1]=p32[j[u]*3+1]; qx[u][2]=p32[j[u]*3+2];
            kx[u] = xk[(size_t)j[u]*64+lane];
        }
        #pragma unroll
        for (int u=0;u<4;++u){
            float rx = qx[u][0]-px, ry = qx[u][1]-py, rz = qx[u][2]-pz;
            float h0 = bb0 + rx*w00 + ry*w10 + rz*w20;
            float h1 = bb1 + rx*w01 + ry*w11 + rz*w21;
            float h2 = bb2 + rx*w02 + ry*w12 + rz*w22;
            float r0 = fmaxf(h0*sc0+sh0, 0.f), r1 = fmaxf(h1*sc1+sh1,0.f), r2 = fmaxf(h2*sc2+sh2,0.f);
            float pr = r0*wa + r1*wb + r2*wc + bpc;
            float rv = kx[u] - xql + pr;
            asum += rv; asq += rv*rv;
        }
    }
    __shared__ float red[4][128];
    red[wvi][lane] = asum; red[wvi][64+lane] = asq;
    __syncthreads();
    if (tid < 128)
        part2[(size_t)tid*2048 + blockIdx.x] = red[0][tid]+red[1][tid]+red[2][tid]+red[3][tid];
}

// ---------------------------------------------------------------- BN3 stats over w (+ wbuf store)
__global__ __launch_bounds__(256) void k_wstats(
    const float* __restrict__ p32,
    const float* __restrict__ xq, const float* __restrict__ xk, const int* __restrict__ idx_k,
    const float* __restrict__ bn1aff, const float* __restrict__ prm,
    const float* __restrict__ bn2aff, float* __restrict__ wbuf, float* __restrict__ part3)
{
    __shared__ float4 PRW[64];
    __shared__ float2 SS2[64];
    __shared__ float4 W1A[64], W1B[64];
    const int tid = threadIdx.x;
    if (tid < 64){
        PRW[tid] = make_float4(prm[O_WP2+tid], prm[O_WP2+64+tid], prm[O_WP2+128+tid], prm[O_BP2+tid]);
        SS2[tid] = make_float2(bn2aff[tid], bn2aff[64+tid]);
        W1A[tid] = make_float4(prm[O_WW1+tid*8+0],prm[O_WW1+tid*8+1],prm[O_WW1+tid*8+2],prm[O_WW1+tid*8+3]);
        W1B[tid] = make_float4(prm[O_WW1+tid*8+4],prm[O_WW1+tid*8+5],prm[O_WW1+tid*8+6],prm[O_WW1+tid*8+7]);
    }
    __syncthreads();
    const int g = blockIdx.x*256 + tid;
    const int n = g >> 4;
    const int j = idx_k[g] & IMASK;
    const float w00=prm[O_WP1+0], w01=prm[O_WP1+1], w02=prm[O_WP1+2];
    const float w10=prm[O_WP1+3], w11=prm[O_WP1+4], w12=prm[O_WP1+5];
    const float w20=prm[O_WP1+6], w21=prm[O_WP1+7], w22=prm[O_WP1+8];
    const float bb0=prm[O_BP1+0], bb1=prm[O_BP1+1], bb2=prm[O_BP1+2];
    const float sc0=bn1aff[0], sc1=bn1aff[1], sc2=bn1aff[2];
    const float sh0=bn1aff[3], sh1=bn1aff[4], sh2=bn1aff[5];
    float rx = p32[j*3+0] - p32[n*3+0];
    float ry = p32[j*3+1] - p32[n*3+1];
    float rz = p32[j*3+2] - p32[n*3+2];
    float h0 = bb0 + rx*w00 + ry*w10 + rz*w20;
    float h1 = bb1 + rx*w01 + ry*w11 + rz*w21;
    float h2 = bb2 + rx*w02 + ry*w12 + rz*w22;
    float r0 = fmaxf(h0*sc0+sh0, 0.f), r1 = fmaxf(h1*sc1+sh1,0.f), r2 = fmaxf(h2*sc2+sh2,0.f);
    float wacc[8];
    #pragma unroll
    for (int i=0;i<8;++i) wacc[i] = prm[O_BW1+i];
    const float4* kr = (const float4*)(xk + (size_t)j*64);
    const float4* qr = (const float4*)(xq + (size_t)n*64);
    #pragma unroll
    for (int c4=0;c4<16;++c4){
        float4 kv = kr[c4], qv = qr[c4];
        float kvv[4] = {kv.x,kv.y,kv.z,kv.w};
        float qvv[4] = {qv.x,qv.y,qv.z,qv.w};
        #pragma unroll
        for (int d=0; d<4; ++d){
            int c = 4*c4 + d;
            float4 pw = PRW[c]; float2 ss = SS2[c];
            float pr = r0*pw.x + r1*pw.y + r2*pw.z + pw.w;
            float rr = kvv[d] - qvv[d] + pr;
            float y = fmaxf(rr*ss.x + ss.y, 0.f);
            float4 wA = W1A[c], wB = W1B[c];
            wacc[0]+=y*wA.x; wacc[1]+=y*wA.y; wacc[2]+=y*wA.z; wacc[3]+=y*wA.w;
            wacc[4]+=y*wB.x; wacc[5]+=y*wB.y; wacc[6]+=y*wB.z; wacc[7]+=y*wB.w;
        }
    }
    *(float4*)&wbuf[(size_t)g*8]   = make_float4(wacc[0],wacc[1],wacc[2],wacc[3]);
    *(float4*)&wbuf[(size_t)g*8+4] = make_float4(wacc[4],wacc[5],wacc[6],wacc[7]);
    float st[16];
    #pragma unroll
    for (int i=0;i<8;++i){ st[i]=wacc[i]; st[8+i]=wacc[i]*wacc[i]; }
    for (int off=32; off; off>>=1){
        #pragma unroll
        for (int k=0;k<16;++k) st[k] += __shfl_down(st[k], off);
    }
    __shared__ float red[4][16];
    const int lane = tid&63, wvi = tid>>6;
    if (lane==0){
        #pragma unroll
        for (int k=0;k<16;++k) red[wvi][k]=st[k];
    }
    __syncthreads();
    if (tid < 16)
        part3[(size_t)tid*2048 + blockIdx.x] = red[0][tid]+red[1][tid]+red[2][tid]+red[3][tid];
}

// ---------------------------------------------------------------- final (reads wbuf; no shfl chain)
__global__ __launch_bounds__(256) void k_out(
    const float* __restrict__ p32, const float* __restrict__ xv,
    const int* __restrict__ idx_k, const int* __restrict__ idx_v,
    const float* __restrict__ bn1aff, const float* __restrict__ prm,
    const float* __restrict__ wbuf, const float* __restrict__ bn3aff,
    const int* __restrict__ flags, void* __restrict__ out)
{
    const int tid = threadIdx.x, lane = tid & 63, wvi = tid >> 6;
    const int n = blockIdx.x*4 + wvi;
    const int f32 = flags[0];
    const float w00=prm[O_WP1+0], w01=prm[O_WP1+1], w02=prm[O_WP1+2];
    const float w10=prm[O_WP1+3], w11=prm[O_WP1+4], w12=prm[O_WP1+5];
    const float w20=prm[O_WP1+6], w21=prm[O_WP1+7], w22=prm[O_WP1+8];
    const float bb0=prm[O_BP1+0], bb1=prm[O_BP1+1], bb2=prm[O_BP1+2];
    const float sc0=bn1aff[0], sc1=bn1aff[1], sc2=bn1aff[2];
    const float sh0=bn1aff[3], sh1=bn1aff[4], sh2=bn1aff[5];
    const float wa=prm[O_WP2+lane], wb=prm[O_WP2+64+lane], wc=prm[O_WP2+128+lane];
    const float bpc=prm[O_BP2+lane];
    const int i = lane & 7;
    float s3[8], t3[8], w2col[8];
    #pragma unroll
    for (int m=0;m<8;++m){
        s3[m]=bn3aff[m]; t3[m]=bn3aff[8+m];
        w2col[m]=prm[O_WW2+m*8+i];
    }
    const float bw2i = prm[O_BW2+i];
    const float px=p32[n*3+0], py=p32[n*3+1], pz=p32[n*3+2];
    float comb[16], wf[16];
    #pragma unroll
    for (int t=0;t<16;++t){
        const int g = n*16 + t;
        const int jk = idx_k[g] & IMASK;
        const int jv = idx_v[g] & IMASK;
        float rx=p32[jk*3+0]-px, ry=p32[jk*3+1]-py, rz=p32[jk*3+2]-pz;
        float h0=bb0+rx*w00+ry*w10+rz*w20;
        float h1=bb1+rx*w01+ry*w11+rz*w21;
        float h2=bb2+rx*w02+ry*w12+rz*w22;
        float r0=fmaxf(h0*sc0+sh0,0.f), r1=fmaxf(h1*sc1+sh1,0.f), r2=fmaxf(h2*sc2+sh2,0.f);
        float pr=r0*wa+r1*wb+r2*wc+bpc;
        float4 wA = *(const float4*)&wbuf[(size_t)g*8];
        float4 wB = *(const float4*)&wbuf[(size_t)g*8+4];
        float wm[8] = {wA.x,wA.y,wA.z,wA.w,wB.x,wB.y,wB.z,wB.w};
        float acc = bw2i;
        #pragma unroll
        for (int m=0;m<8;++m){
            float y3 = fmaxf(wm[m]*s3[m]+t3[m],0.f);
            acc += y3*w2col[m];
        }
        wf[t]=acc;
        comb[t]=xv[(size_t)jv*64+lane]+pr;
    }
    float mx = wf[0];
    #pragma unroll
    for (int t=1;t<16;++t) mx = fmaxf(mx, wf[t]);
    float ssum=0.f, osum=0.f;
    #pragma unroll
    for (int t=0;t<16;++t){ float e = __expf(wf[t]-mx); ssum += e; osum += e*comb[t]; }
    const float v = osum / ssum;
    if (f32) ((float*)out)[(size_t)n*64+lane] = v;
    else     ((bf16*)out)[(size_t)n*64+lane] = __float2bfloat16(v);
}

// ---------------------------------------------------------------- launcher
extern "C" void kernel_launch(void* const* d_in, const int* in_sizes, int n_in,
                              void* d_out, int out_size, void* d_ws, size_t ws_size,
                              hipStream_t stream)
{
    const void* p  = d_in[0];
    const void* x  = d_in[1];
    P20 prms;
    for (int i = 0; i < 20; ++i) prms.p[i] = d_in[3+i];

    // workspace layout (floats) — within the 48.08 MB proven footprint
    float* W = (float*)d_ws;
    float* xqf    = W + 0;
    float* xkf    = W + 2097152;
    float* xvf    = W + 4194304;
    float* sqk    = W + 6291456;
    float* sqv    = W + 6324224;
    int*   idx_k  = (int*)(W + 6356992);
    int*   idx_v  = (int*)(W + 6881280);
    float* p32    = W + 7405568;   // 98304
    float* prm    = W + 7503872;   // 13490 (+pad)
    float* part1  = W + 7517376;   // transposed [6][512] = 3072 (slot 12288)
    float* part2  = W + 7529664;   // transposed [128][2048] = 262144
    float* part3  = W + 7791808;   // transposed [16][2048] = 32768
    float* bn1aff = W + 7824576;   // 16
    float* bn2aff = W + 7824592;   // 128
    float* bn3aff = W + 7824720;   // 16
    int*   flags  = (int*)(W + 7824736); // 2 (+pad to 16)
    // overlay region (4,194,304 floats): bf16 h/m planes (live: k_proj -> k_knn_part),
    // then wbuf (written k_wstats, read k_out) — disjoint lifetimes.
    unsigned* hkp = (unsigned*)(W + 7824752);             // 1,048,576 u32
    unsigned* mkp = (unsigned*)(W + 7824752 + 1048576);
    unsigned* hvp = (unsigned*)(W + 7824752 + 2097152);
    unsigned* mvp = (unsigned*)(W + 7824752 + 3145728);
    float* wbuf   = W + 7824752;   // 4,194,304

    const float invP = 1.f / (float)NPAIR;

    k_sniff<<<1,256,0,stream>>>(x, d_in[3], flags);
    k_conv<<<(NPRM + NPTS*3 + 255)/256,256,0,stream>>>(prms, p, flags, prm, p32);
    k_proj<<<2048,256,0,stream>>>(x, flags, prm, xqf,xkf,xvf, sqk,sqv, hkp,mkp,hvp,mvp);
    k_knn_part<<<1024,256,0,stream>>>(xkf, xvf, hkp,mkp,hvp,mvp, sqk, sqv,
                                      p32, prm, idx_k, idx_v, part1);
    k_bnred_par<<<3,256,0,stream>>>(part1, 512, 3, prm+O_GP, prm+O_BTP, bn1aff, invP);
    k_rstats<<<2048,256,0,stream>>>(p32, xqf, xkf, idx_k, bn1aff, prm, part2);
    k_bnred_par<<<64,256,0,stream>>>(part2, 2048, 64, prm+O_G1, prm+O_BT1, bn2aff, invP);
    k_wstats<<<2048,256,0,stream>>>(p32, xqf, xkf, idx_k, bn1aff, prm, bn2aff, wbuf, part3);
    k_bnred_par<<<8,256,0,stream>>>(part3, 2048, 8, prm+O_G2, prm+O_BT2, bn3aff, invP);
    k_out<<<8192,256,0,stream>>>(p32, xvf, idx_k, idx_v, bn1aff, prm,
                                 wbuf, bn3aff, flags, d_out);
}